// Round 4
// baseline (1140.292 us; speedup 1.0000x reference)
//
#include <hip/hip_runtime.h>
#include <math.h>

#define BB 128
#define SS 1024
#define MM 64
#define KDIM 128
#define VDIM 256
#define FDIM 128
#define QNUM 5000
#define QD 5001            // q ids 0..5000
#define RROWS (4 * QD)     // 20004 distinct (r,q) rows

typedef _Float16 half2_t __attribute__((ext_vector_type(2)));
union U4 { uint4 u; half2_t h[4]; };

#if defined(__has_builtin)
#if __has_builtin(__builtin_amdgcn_fdot2)
#define HAVE_FDOT2 1
#endif
#endif

__device__ __forceinline__ float dot2_(half2_t a, half2_t b, float c) {
#ifdef HAVE_FDOT2
  return __builtin_amdgcn_fdot2(a, b, c, false);
#else
  return c + (float)a[0] * (float)b[0] + (float)a[1] * (float)b[1];
#endif
}

__device__ __forceinline__ float sigmoidf_(float x) { return 1.0f / (1.0f + expf(-x)); }
__device__ __forceinline__ float softplusf_(float x) { return (x > 20.0f) ? x : log1pf(expf(x)); }

// ---------------- K0: W_summary read-part -> f16, [f][k] layout ----------------
__global__ __launch_bounds__(256) void k_prep(const float* __restrict__ W_summary,
                                              _Float16* __restrict__ Wh)
{
  const int e = blockIdx.x * 256 + threadIdx.x;   // 0..32767
  const int f = e >> 8, k = e & 255;
  Wh[(size_t)f * 256 + k] = (_Float16)W_summary[(size_t)k * FDIM + f];
}

// ---------------- K1: E/A table over all (r,q): 20004 rows, packed float2 ----------------
__global__ __launch_bounds__(256) void k_ea(
    const float* __restrict__ Wv, const float* __restrict__ bv,
    const float* __restrict__ We, const float* __restrict__ be,
    const float* __restrict__ Wa, const float* __restrict__ ba,
    float2* __restrict__ EA)
{
  const int tid = threadIdx.x;
  const int base = blockIdx.x * 32;
  __shared__ float sve[32][256];
#pragma unroll
  for (int j = 0; j < 32; ++j) {
    const int rr = base + j;
    float v = bv[tid];
    if (rr < RROWS) {
      const int q = rr % QD;
      const int r = rr / QD;
      if (q >= 1) {
        const float sc = (float)r * (1.0f / 3.0f);
        v += Wv[(size_t)(q - 1) * VDIM + tid] + sc * Wv[(size_t)(QNUM + q - 1) * VDIM + tid];
      }
    }
    sve[j][tid] = v;
  }
  __syncthreads();
  float ea[32], aa[32];
#pragma unroll
  for (int j = 0; j < 32; ++j) { ea[j] = 0.f; aa[j] = 0.f; }
#pragma unroll 4
  for (int i = 0; i < 256; ++i) {
    const float we = We[i * VDIM + tid];
    const float wa = Wa[i * VDIM + tid];
#pragma unroll
    for (int j = 0; j < 32; ++j) {
      ea[j] = fmaf(sve[j][i], we, ea[j]);
      aa[j] = fmaf(sve[j][i], wa, aa[j]);
    }
  }
  const float bev = be[tid], bav = ba[tid];
#pragma unroll
  for (int j = 0; j < 32; ++j) {
    const int rr = base + j;
    if (rr < RROWS) {
      float2 p;
      p.x = sigmoidf_(ea[j] + bev);
      p.y = tanhf(aa[j] + bav);
      EA[(size_t)rr * VDIM + tid] = p;
    }
  }
}

// ---------------- K2: per-q tables: w (softmax), Sq, aq, betas ----------------
__global__ __launch_bounds__(256) void k_q(
    const float* __restrict__ q_embed, const float* __restrict__ key_mem,
    const float* __restrict__ W_summary, const float* __restrict__ b_summary,
    const float* __restrict__ W_disc,
    const float* __restrict__ W_beta, const float* __restrict__ b_beta,
    float* __restrict__ w_tab, float* __restrict__ Sq_tab,
    float* __restrict__ aq_tab, float* __restrict__ beta_tab)
{
  const int q = blockIdx.x;
  const int tid = threadIdx.x;
  const int wave = tid >> 6, l = tid & 63;
  __shared__ float qe[KDIM];
  __shared__ float slog[MM];
  if (tid < KDIM) qe[tid] = q_embed[(size_t)q * KDIM + tid];
  __syncthreads();
  {
    const int m = tid >> 2, j = tid & 3;
    const float* krow = key_mem + m * KDIM + j * 32;
    const float* qrow = qe + j * 32;
    float acc = 0.f;
#pragma unroll
    for (int k = 0; k < 32; ++k) {
      const int i = (k + tid) & 31;
      acc = fmaf(qrow[i], krow[i], acc);
    }
    acc += __shfl_xor(acc, 1);
    acc += __shfl_xor(acc, 2);
    if (j == 0) slog[m] = acc;
  }
  __syncthreads();
  if (wave == 0) {
    const float x = slog[l];
    float mx = x;
#pragma unroll
    for (int o = 32; o; o >>= 1) mx = fmaxf(mx, __shfl_xor(mx, o));
    const float e = expf(x - mx);
    float s = e;
#pragma unroll
    for (int o = 32; o; o >>= 1) s += __shfl_xor(s, o);
    w_tab[(size_t)q * MM + l] = e / s;
  } else if (wave == 1) {
    float p = qe[l] * W_disc[KDIM + l] + qe[64 + l] * W_disc[KDIM + 64 + l];
#pragma unroll
    for (int o = 32; o; o >>= 1) p += __shfl_xor(p, o);
    if (l == 0) aq_tab[q] = p;
  } else if (wave == 2) {
    float p0 = qe[l] * W_beta[l * 3 + 0] + qe[64 + l] * W_beta[(64 + l) * 3 + 0];
    float p1 = qe[l] * W_beta[l * 3 + 1] + qe[64 + l] * W_beta[(64 + l) * 3 + 1];
    float p2 = qe[l] * W_beta[l * 3 + 2] + qe[64 + l] * W_beta[(64 + l) * 3 + 2];
#pragma unroll
    for (int o = 32; o; o >>= 1) {
      p0 += __shfl_xor(p0, o); p1 += __shfl_xor(p1, o); p2 += __shfl_xor(p2, o);
    }
    if (l == 0) {
      beta_tab[(size_t)q * 3 + 0] = p0 + b_beta[0];
      beta_tab[(size_t)q * 3 + 1] = p1 + b_beta[1];
      beta_tab[(size_t)q * 3 + 2] = p2 + b_beta[2];
    }
  }
  {
    const int f = tid >> 1, h = tid & 1;
    float acc = 0.f;
#pragma unroll 8
    for (int ii = 0; ii < 64; ++ii)
      acc = fmaf(qe[h * 64 + ii], W_summary[(size_t)(VDIM + h * 64 + ii) * FDIM + f], acc);
    acc += __shfl_xor(acc, 1);
    if (h == 0) Sq_tab[(size_t)q * FDIM + f] = acc + b_summary[f];
  }
}

// ---------------- K3: chunked-scan recurrence, one 8-wave block per (b, vchunk) ----------------
// wave 0: replay [0,240) from init; waves 1..7: (D,U) over 112-step chunks, LDS scan, replay.
__global__ __launch_bounds__(512, 2) void k_rec2(
    const int* __restrict__ q_data, const int* __restrict__ r_data,
    const float* __restrict__ init_mv,
    const float2* __restrict__ EA, const float* __restrict__ w_tab,
    _Float16* __restrict__ Rd)
{
  const int tid = threadIdx.x;
  const int wave = tid >> 6, lane = tid & 63;
  const int b = blockIdx.x >> 2, vc = blockIdx.x & 3;
  const int v = vc * 64 + lane;

  __shared__ int s_q[SS];
  __shared__ int s_r[SS];
  __shared__ __align__(16) float s_w[8][8][MM];   // per-wave ring (wave-synchronous, no barriers)
  __shared__ float s_R[MM * 64];                  // running boundary state [m][lane]

  for (int i = tid; i < SS; i += 512) {
    s_q[i] = q_data[b * SS + i];
    s_r[i] = r_data[b * SS + i];
  }
  __syncthreads();

  const int tb  = (wave == 0) ? 0 : (240 + (wave - 1) * 112);
  const int len = (wave == 0) ? 240 : 112;

  float mv[MM];
  float D[MM], U[MM];

  // ---- replay: evolve mv, store reads (no barriers; ring is per-wave) ----
  auto replay = [&](int base, int n) {
    float eD[4], aD[4];
#pragma unroll
    for (int j = 0; j < 4; ++j) {
      const int t = base + j;
      const int q = s_q[t];
      const float2 ea = EA[((size_t)(s_r[t] * QD + q)) * VDIM + v];
      eD[j] = ea.x; aD[j] = ea.y;
      s_w[wave][j][lane] = w_tab[(size_t)q * MM + lane];
    }
    const int ng = n >> 2;
    for (int g = 0; g < ng; ++g) {
      const int cb = (g & 1) << 2, nb = ((g + 1) & 1) << 2;
      float eN[4], aN[4];
#pragma unroll
      for (int j = 0; j < 4; ++j) {
        int tp = base + g * 4 + 4 + j; if (tp >= base + n) tp = base + n - 1;
        const int q = s_q[tp];
        const float2 ea = EA[((size_t)(s_r[tp] * QD + q)) * VDIM + v];
        eN[j] = ea.x; aN[j] = ea.y;
        s_w[wave][nb + j][lane] = w_tab[(size_t)q * MM + lane];
      }
#pragma unroll
      for (int j = 0; j < 4; ++j) {
        const float4* w4 = (const float4*)s_w[wave][cb + j];
        const float e = eD[j], a = aD[j];
        float r0 = 0.f, r1 = 0.f, r2 = 0.f, r3 = 0.f;
#pragma unroll
        for (int k = 0; k < 16; ++k) {
          const float4 ww = w4[k];
          float t0;
          r0 = fmaf(ww.x, mv[4 * k + 0], r0);
          t0 = fmaf(-e, mv[4 * k + 0], a); mv[4 * k + 0] = fmaf(ww.x, t0, mv[4 * k + 0]);
          r1 = fmaf(ww.y, mv[4 * k + 1], r1);
          t0 = fmaf(-e, mv[4 * k + 1], a); mv[4 * k + 1] = fmaf(ww.y, t0, mv[4 * k + 1]);
          r2 = fmaf(ww.z, mv[4 * k + 2], r2);
          t0 = fmaf(-e, mv[4 * k + 2], a); mv[4 * k + 2] = fmaf(ww.z, t0, mv[4 * k + 2]);
          r3 = fmaf(ww.w, mv[4 * k + 3], r3);
          t0 = fmaf(-e, mv[4 * k + 3], a); mv[4 * k + 3] = fmaf(ww.w, t0, mv[4 * k + 3]);
        }
        Rd[((size_t)b * SS + base + g * 4 + j) * VDIM + v] = (_Float16)((r0 + r1) + (r2 + r3));
      }
#pragma unroll
      for (int j = 0; j < 4; ++j) { eD[j] = eN[j]; aD[j] = aN[j]; }
    }
  };

  // ---- accum: chunk transfer (D,U) without state ----
  auto accum = [&](int base, int n) {
    float eD[4], aD[4];
#pragma unroll
    for (int j = 0; j < 4; ++j) {
      const int t = base + j;
      const int q = s_q[t];
      const float2 ea = EA[((size_t)(s_r[t] * QD + q)) * VDIM + v];
      eD[j] = ea.x; aD[j] = ea.y;
      s_w[wave][j][lane] = w_tab[(size_t)q * MM + lane];
    }
    const int ng = n >> 2;
    for (int g = 0; g < ng; ++g) {
      const int cb = (g & 1) << 2, nb = ((g + 1) & 1) << 2;
      float eN[4], aN[4];
#pragma unroll
      for (int j = 0; j < 4; ++j) {
        int tp = base + g * 4 + 4 + j; if (tp >= base + n) tp = base + n - 1;
        const int q = s_q[tp];
        const float2 ea = EA[((size_t)(s_r[tp] * QD + q)) * VDIM + v];
        eN[j] = ea.x; aN[j] = ea.y;
        s_w[wave][nb + j][lane] = w_tab[(size_t)q * MM + lane];
      }
#pragma unroll
      for (int j = 0; j < 4; ++j) {
        const float4* w4 = (const float4*)s_w[wave][cb + j];
        const float e = eD[j], a = aD[j];
#pragma unroll
        for (int k = 0; k < 16; ++k) {
          const float4 ww = w4[k];
          float c;
          c = ww.x * e; D[4 * k + 0] = fmaf(-c, D[4 * k + 0], D[4 * k + 0]);
          U[4 * k + 0] = fmaf(-c, U[4 * k + 0], U[4 * k + 0]); U[4 * k + 0] = fmaf(ww.x, a, U[4 * k + 0]);
          c = ww.y * e; D[4 * k + 1] = fmaf(-c, D[4 * k + 1], D[4 * k + 1]);
          U[4 * k + 1] = fmaf(-c, U[4 * k + 1], U[4 * k + 1]); U[4 * k + 1] = fmaf(ww.y, a, U[4 * k + 1]);
          c = ww.z * e; D[4 * k + 2] = fmaf(-c, D[4 * k + 2], D[4 * k + 2]);
          U[4 * k + 2] = fmaf(-c, U[4 * k + 2], U[4 * k + 2]); U[4 * k + 2] = fmaf(ww.z, a, U[4 * k + 2]);
          c = ww.w * e; D[4 * k + 3] = fmaf(-c, D[4 * k + 3], D[4 * k + 3]);
          U[4 * k + 3] = fmaf(-c, U[4 * k + 3], U[4 * k + 3]); U[4 * k + 3] = fmaf(ww.w, a, U[4 * k + 3]);
        }
      }
#pragma unroll
      for (int j = 0; j < 4; ++j) { eD[j] = eN[j]; aD[j] = aN[j]; }
    }
  };

  // ---- phase 1 ----
  if (wave == 0) {
#pragma unroll
    for (int m = 0; m < MM; ++m) mv[m] = init_mv[m * VDIM + v];
    replay(tb, len);
#pragma unroll
    for (int m = 0; m < MM; ++m) s_R[m * 64 + lane] = mv[m];
  } else {
#pragma unroll
    for (int m = 0; m < MM; ++m) { D[m] = 1.f; U[m] = 0.f; }
    accum(tb, len);
  }

  // ---- phase 2: sequential boundary scan across waves ----
  for (int rr = 1; rr < 8; ++rr) {
    __syncthreads();
    if (wave == rr) {
#pragma unroll
      for (int m = 0; m < MM; ++m) {
        const float x = s_R[m * 64 + lane];
        s_R[m * 64 + lane] = fmaf(x, D[m], U[m]);
        mv[m] = x;
      }
    }
  }

  // ---- phase 3: replay chunks 1..7 from boundary states ----
  if (wave > 0) replay(tb, len);
}

// ---------------- K4: parallel summary GEMM + heads + CORAL over all (b,t) ----------------
__global__ __launch_bounds__(256) void k_head(
    const int* __restrict__ q_data,
    const _Float16* __restrict__ Rd, const _Float16* __restrict__ Wh,
    const float* __restrict__ Sq_tab, const float* __restrict__ aq_tab,
    const float* __restrict__ beta_tab,
    const float* __restrict__ W_theta, const float* __restrict__ b_theta,
    const float* __restrict__ W_disc, const float* __restrict__ b_disc,
    const float* __restrict__ W_c1, const float* __restrict__ b_c1,
    const float* __restrict__ W_c2, const float* __restrict__ b_c2,
    const float* __restrict__ coral_w, const float* __restrict__ coral_b,
    float* __restrict__ out)
{
  const int tid = threadIdx.x;
  const int w = tid >> 6, l = tid & 63;
  const int rowbase = blockIdx.x * 64;           // 64 rows (same b: 64 | 1024)
  const int b = rowbase >> 10;
  const int t0 = rowbase & (SS - 1);

  __shared__ __align__(16) _Float16 s_A[64 * 256];   // 32 KB
  __shared__ __align__(16) _Float16 s_sum[64 * 128]; // 16 KB
  __shared__ int   s_q[64];
  __shared__ float s_aq[64];
  __shared__ float s_be[64][3];

  {
    const uint4* src = (const uint4*)(Rd + (size_t)rowbase * VDIM);
    uint4* dst = (uint4*)s_A;
    for (int i = tid; i < (64 * 256 * 2) / 16; i += 256) dst[i] = src[i];
  }
  if (tid < 64) {
    const int q = q_data[b * SS + t0 + tid];
    s_q[tid] = q;
    s_aq[tid] = aq_tab[q];
    s_be[tid][0] = beta_tab[(size_t)q * 3 + 0];
    s_be[tid][1] = beta_tab[(size_t)q * 3 + 1];
    s_be[tid][2] = beta_tab[(size_t)q * 3 + 2];
  }

  const int fp = l >> 1, g = l & 1;
  const int fbase = (w & 1) * 64;
  const int f0 = fbase + 2 * fp, f1 = f0 + 1;
  U4 wr0[16], wr1[16];
  {
    const uint4* p0 = (const uint4*)(Wh + (size_t)f0 * 256 + g * 128);
    const uint4* p1 = (const uint4*)(Wh + (size_t)f1 * 256 + g * 128);
#pragma unroll
    for (int i = 0; i < 16; ++i) { wr0[i].u = p0[i]; wr1[i].u = p1[i]; }
  }
  __syncthreads();

  for (int rp = 0; rp < 32; ++rp) {
    const int r = 2 * rp + (w >> 1);
    const uint4* a4 = (const uint4*)(s_A + r * 256 + g * 128);
    float a0 = 0.f, a1 = 0.f, c0 = 0.f, c1 = 0.f;
#pragma unroll
    for (int i = 0; i < 16; i += 2) {
      U4 x; x.u = a4[i];
      U4 y; y.u = a4[i + 1];
#pragma unroll
      for (int j = 0; j < 4; ++j) {
        a0 = dot2_(x.h[j], wr0[i].h[j], a0);
        a1 = dot2_(x.h[j], wr1[i].h[j], a1);
        c0 = dot2_(y.h[j], wr0[i + 1].h[j], c0);
        c1 = dot2_(y.h[j], wr1[i + 1].h[j], c1);
      }
    }
    float f0acc = a0 + c0, f1acc = a1 + c1;
    f0acc += __shfl_xor(f0acc, 1);
    f1acc += __shfl_xor(f1acc, 1);
    if (g == 0) {
      const float2 sq = *(const float2*)(Sq_tab + (size_t)s_q[r] * FDIM + f0);
      s_sum[r * 128 + f0] = (_Float16)tanhf(f0acc + sq.x);
      s_sum[r * 128 + f1] = (_Float16)tanhf(f1acc + sq.y);
    }
  }
  __syncthreads();

  const float tw0 = W_theta[l], tw1 = W_theta[64 + l], tb = b_theta[0];
  const float dw0 = W_disc[l], dw1 = W_disc[64 + l], db = b_disc[0];
  float wc1reg[5];
#pragma unroll
  for (int i = 0; i < 5; ++i) wc1reg[i] = W_c1[i * 64 + l];
  const float bc1 = b_c1[l];
  const int jj = l >> 1, hh2 = l & 1;
  float wc2reg[32];
#pragma unroll
  for (int i = 0; i < 32; ++i) wc2reg[i] = W_c2[(hh2 * 32 + i) * 32 + jj];
  const float bc2 = b_c2[jj];
  const float cw = coral_w[jj];
  const float cb0 = coral_b[0], cb1 = coral_b[1], cb2 = coral_b[2];

  float* out_theta = out;
  float* out_beta  = out + (size_t)BB * SS;
  float* out_alpha = out + (size_t)BB * SS * 4;
  float* out_probs = out + (size_t)BB * SS * 5;
  float* out_logit = out + (size_t)BB * SS * 9;

  for (int rr = 0; rr < 16; ++rr) {
    const int r = w * 16 + rr;
    const float su0 = (float)s_sum[r * 128 + l];
    const float su1 = (float)s_sum[r * 128 + 64 + l];
    float at = su0 * tw0 + su1 * tw1;
    float ad = su0 * dw0 + su1 * dw1;
#pragma unroll
    for (int o = 32; o; o >>= 1) { at += __shfl_xor(at, o); ad += __shfl_xor(ad, o); }
    const float theta = (at + tb) * 3.0f;
    const float alpha = softplusf_(ad + s_aq[r] + db);
    const float be0 = s_be[r][0], be1 = s_be[r][1], be2 = s_be[r][2];
    float h1 = bc1;
    h1 = fmaf(theta, wc1reg[0], h1);
    h1 = fmaf(alpha, wc1reg[1], h1);
    h1 = fmaf(be0, wc1reg[2], h1);
    h1 = fmaf(be1, wc1reg[3], h1);
    h1 = fmaf(be2, wc1reg[4], h1);
    h1 = fmaxf(h1, 0.f);
    float hacc = hh2 ? 0.f : bc2;
#pragma unroll
    for (int i = 0; i < 32; ++i)
      hacc = fmaf(__shfl(h1, hh2 * 32 + i), wc2reg[i], hacc);
    hacc += __shfl_xor(hacc, 1);
    const float h2 = fmaxf(hacc, 0.f);
    float p = h2 * cw * 0.5f;
#pragma unroll
    for (int o = 32; o; o >>= 1) p += __shfl_xor(p, o);
    if (l == 0) {
      const float z = p;
      const float l0 = z + cb0, l1 = z + cb1, l2 = z + cb2;
      const float s0 = sigmoidf_(l0), s1 = sigmoidf_(l1), s2 = sigmoidf_(l2);
      const float q0 = s0, q1 = s0 * s1, q2 = s0 * s1 * s2;
      const size_t bt = (size_t)rowbase + r;
      out_theta[bt] = theta;
      out_alpha[bt] = alpha;
      out_beta[bt * 3 + 0] = be0;
      out_beta[bt * 3 + 1] = be1;
      out_beta[bt * 3 + 2] = be2;
      out_logit[bt * 3 + 0] = l0;
      out_logit[bt * 3 + 1] = l1;
      out_logit[bt * 3 + 2] = l2;
      out_probs[bt * 4 + 0] = 1.f - q0;
      out_probs[bt * 4 + 1] = q0 - q1;
      out_probs[bt * 4 + 2] = q1 - q2;
      out_probs[bt * 4 + 3] = q2;
    }
  }
}

extern "C" void kernel_launch(void* const* d_in, const int* in_sizes, int n_in,
                              void* d_out, int out_size, void* d_ws, size_t ws_size,
                              hipStream_t stream) {
  const int*   q_data    = (const int*)d_in[0];
  const int*   r_data    = (const int*)d_in[1];
  const float* q_embed   = (const float*)d_in[2];
  const float* key_mem   = (const float*)d_in[3];
  const float* init_mv   = (const float*)d_in[4];
  const float* W_value   = (const float*)d_in[5];
  const float* b_value   = (const float*)d_in[6];
  const float* W_erase   = (const float*)d_in[7];
  const float* b_erase   = (const float*)d_in[8];
  const float* W_add     = (const float*)d_in[9];
  const float* b_add     = (const float*)d_in[10];
  const float* W_summary = (const float*)d_in[11];
  const float* b_summary = (const float*)d_in[12];
  const float* W_theta   = (const float*)d_in[13];
  const float* b_theta   = (const float*)d_in[14];
  const float* W_beta    = (const float*)d_in[15];
  const float* b_beta    = (const float*)d_in[16];
  const float* W_disc    = (const float*)d_in[17];
  const float* b_disc    = (const float*)d_in[18];
  const float* W_c1      = (const float*)d_in[19];
  const float* b_c1      = (const float*)d_in[20];
  const float* W_c2      = (const float*)d_in[21];
  const float* b_c2      = (const float*)d_in[22];
  const float* coral_w   = (const float*)d_in[23];
  const float* coral_b   = (const float*)d_in[24];

  float* ws = (float*)d_ws;
  size_t off = 0;
  float2* EA      = (float2*)(ws + off); off += (size_t)RROWS * VDIM * 2;  // 10,242,048 floats
  float* w_tab    = ws + off; off += (size_t)QD * MM;
  float* Sq_tab   = ws + off; off += (size_t)QD * FDIM;
  float* aq_tab   = ws + off; off += 5120;
  float* beta_tab = ws + off; off += 15104;
  _Float16* Wh = (_Float16*)(ws + off); off += (VDIM * FDIM) / 2;
  _Float16* Rd = (_Float16*)(ws + off);

  k_prep<<<dim3(128), dim3(256), 0, stream>>>(W_summary, Wh);

  k_ea<<<dim3((RROWS + 31) / 32), dim3(256), 0, stream>>>(
      W_value, b_value, W_erase, b_erase, W_add, b_add, EA);

  k_q<<<dim3(QD), dim3(256), 0, stream>>>(
      q_embed, key_mem, W_summary, b_summary, W_disc, W_beta, b_beta,
      w_tab, Sq_tab, aq_tab, beta_tab);

  k_rec2<<<dim3(BB * 4), dim3(512), 0, stream>>>(
      q_data, r_data, init_mv, EA, w_tab, Rd);

  k_head<<<dim3((BB * SS) / 64), dim3(256), 0, stream>>>(
      q_data, Rd, Wh, Sq_tab, aq_tab, beta_tab,
      W_theta, b_theta, W_disc, b_disc,
      W_c1, b_c1, W_c2, b_c2, coral_w, coral_b, (float*)d_out);
}

// Round 5
// 1055.003 us; speedup vs baseline: 1.0808x; 1.0808x over previous
//
#include <hip/hip_runtime.h>
#include <math.h>

#define BB 128
#define SS 1024
#define MM 64
#define KDIM 128
#define VDIM 256
#define FDIM 128
#define QNUM 5000
#define QD 5001            // q ids 0..5000
#define RROWS (4 * QD)     // 20004 distinct (r,q) rows

#define L0 156             // wave-0 chunk (replay-only, 3 ops/elem)
#define LC 124             // waves 1..7 chunk (accum 4 + replay 3 ops/elem)

typedef _Float16 half2_t __attribute__((ext_vector_type(2)));
union U4 { uint4 u; half2_t h[4]; };

#if defined(__has_builtin)
#if __has_builtin(__builtin_amdgcn_fdot2)
#define HAVE_FDOT2 1
#endif
#endif

__device__ __forceinline__ float dot2_(half2_t a, half2_t b, float c) {
#ifdef HAVE_FDOT2
  return __builtin_amdgcn_fdot2(a, b, c, false);
#else
  return c + (float)a[0] * (float)b[0] + (float)a[1] * (float)b[1];
#endif
}

__device__ __forceinline__ float sigmoidf_(float x) { return 1.0f / (1.0f + expf(-x)); }
__device__ __forceinline__ float softplusf_(float x) { return (x > 20.0f) ? x : log1pf(expf(x)); }

// ---------------- K0: W_summary read-part -> f16, [f][k] layout ----------------
__global__ __launch_bounds__(256) void k_prep(const float* __restrict__ W_summary,
                                              _Float16* __restrict__ Wh)
{
  const int e = blockIdx.x * 256 + threadIdx.x;   // 0..32767
  const int f = e >> 8, k = e & 255;
  Wh[(size_t)f * 256 + k] = (_Float16)W_summary[(size_t)k * FDIM + f];
}

// ---------------- K1: E/A table over all (r,q): 20004 rows, packed float2 ----------------
__global__ __launch_bounds__(256) void k_ea(
    const float* __restrict__ Wv, const float* __restrict__ bv,
    const float* __restrict__ We, const float* __restrict__ be,
    const float* __restrict__ Wa, const float* __restrict__ ba,
    float2* __restrict__ EA)
{
  const int tid = threadIdx.x;
  const int base = blockIdx.x * 32;
  __shared__ float sve[32][256];
#pragma unroll
  for (int j = 0; j < 32; ++j) {
    const int rr = base + j;
    float v = bv[tid];
    if (rr < RROWS) {
      const int q = rr % QD;
      const int r = rr / QD;
      if (q >= 1) {
        const float sc = (float)r * (1.0f / 3.0f);
        v += Wv[(size_t)(q - 1) * VDIM + tid] + sc * Wv[(size_t)(QNUM + q - 1) * VDIM + tid];
      }
    }
    sve[j][tid] = v;
  }
  __syncthreads();
  float ea[32], aa[32];
#pragma unroll
  for (int j = 0; j < 32; ++j) { ea[j] = 0.f; aa[j] = 0.f; }
#pragma unroll 4
  for (int i = 0; i < 256; ++i) {
    const float we = We[i * VDIM + tid];
    const float wa = Wa[i * VDIM + tid];
#pragma unroll
    for (int j = 0; j < 32; ++j) {
      ea[j] = fmaf(sve[j][i], we, ea[j]);
      aa[j] = fmaf(sve[j][i], wa, aa[j]);
    }
  }
  const float bev = be[tid], bav = ba[tid];
#pragma unroll
  for (int j = 0; j < 32; ++j) {
    const int rr = base + j;
    if (rr < RROWS) {
      float2 p;
      p.x = sigmoidf_(ea[j] + bev);
      p.y = tanhf(aa[j] + bav);
      EA[(size_t)rr * VDIM + tid] = p;
    }
  }
}

// ---------------- K2: per-q tables: w (softmax), Sq, aq, betas ----------------
__global__ __launch_bounds__(256) void k_q(
    const float* __restrict__ q_embed, const float* __restrict__ key_mem,
    const float* __restrict__ W_summary, const float* __restrict__ b_summary,
    const float* __restrict__ W_disc,
    const float* __restrict__ W_beta, const float* __restrict__ b_beta,
    float* __restrict__ w_tab, float* __restrict__ Sq_tab,
    float* __restrict__ aq_tab, float* __restrict__ beta_tab)
{
  const int q = blockIdx.x;
  const int tid = threadIdx.x;
  const int wave = tid >> 6, l = tid & 63;
  __shared__ float qe[KDIM];
  __shared__ float slog[MM];
  if (tid < KDIM) qe[tid] = q_embed[(size_t)q * KDIM + tid];
  __syncthreads();
  {
    const int m = tid >> 2, j = tid & 3;
    const float* krow = key_mem + m * KDIM + j * 32;
    const float* qrow = qe + j * 32;
    float acc = 0.f;
#pragma unroll
    for (int k = 0; k < 32; ++k) {
      const int i = (k + tid) & 31;
      acc = fmaf(qrow[i], krow[i], acc);
    }
    acc += __shfl_xor(acc, 1);
    acc += __shfl_xor(acc, 2);
    if (j == 0) slog[m] = acc;
  }
  __syncthreads();
  if (wave == 0) {
    const float x = slog[l];
    float mx = x;
#pragma unroll
    for (int o = 32; o; o >>= 1) mx = fmaxf(mx, __shfl_xor(mx, o));
    const float e = expf(x - mx);
    float s = e;
#pragma unroll
    for (int o = 32; o; o >>= 1) s += __shfl_xor(s, o);
    w_tab[(size_t)q * MM + l] = e / s;
  } else if (wave == 1) {
    float p = qe[l] * W_disc[KDIM + l] + qe[64 + l] * W_disc[KDIM + 64 + l];
#pragma unroll
    for (int o = 32; o; o >>= 1) p += __shfl_xor(p, o);
    if (l == 0) aq_tab[q] = p;
  } else if (wave == 2) {
    float p0 = qe[l] * W_beta[l * 3 + 0] + qe[64 + l] * W_beta[(64 + l) * 3 + 0];
    float p1 = qe[l] * W_beta[l * 3 + 1] + qe[64 + l] * W_beta[(64 + l) * 3 + 1];
    float p2 = qe[l] * W_beta[l * 3 + 2] + qe[64 + l] * W_beta[(64 + l) * 3 + 2];
#pragma unroll
    for (int o = 32; o; o >>= 1) {
      p0 += __shfl_xor(p0, o); p1 += __shfl_xor(p1, o); p2 += __shfl_xor(p2, o);
    }
    if (l == 0) {
      beta_tab[(size_t)q * 3 + 0] = p0 + b_beta[0];
      beta_tab[(size_t)q * 3 + 1] = p1 + b_beta[1];
      beta_tab[(size_t)q * 3 + 2] = p2 + b_beta[2];
    }
  }
  {
    const int f = tid >> 1, h = tid & 1;
    float acc = 0.f;
#pragma unroll 8
    for (int ii = 0; ii < 64; ++ii)
      acc = fmaf(qe[h * 64 + ii], W_summary[(size_t)(VDIM + h * 64 + ii) * FDIM + f], acc);
    acc += __shfl_xor(acc, 1);
    if (h == 0) Sq_tab[(size_t)q * FDIM + f] = acc + b_summary[f];
  }
}

// ---------------- K3: chunked-scan recurrence, m-split accum to avoid spills ----------------
// wave 0: replay [0,L0) from init; waves 1..7: (D,U) over LC-step chunks in two
// 32-m passes (64 scan regs live, not 128), boundary scan per pass, then replay.
__global__ __launch_bounds__(512, 2) void k_rec3(
    const int* __restrict__ q_data, const int* __restrict__ r_data,
    const float* __restrict__ init_mv,
    const float2* __restrict__ EA, const float* __restrict__ w_tab,
    _Float16* __restrict__ Rd)
{
  const int tid = threadIdx.x;
  const int wave = tid >> 6, lane = tid & 63;
  const int b = blockIdx.x >> 2, vc = blockIdx.x & 3;
  const int v = vc * 64 + lane;

  __shared__ int s_q[SS];
  __shared__ int s_r[SS];
  __shared__ __align__(16) float s_w[8][8][MM];   // per-wave ring (wave-synchronous)
  __shared__ float s_R[MM * 64];                  // running boundary state [m][lane]

  for (int i = tid; i < SS; i += 512) {
    s_q[i] = q_data[b * SS + i];
    s_r[i] = r_data[b * SS + i];
  }
  __syncthreads();

  const int tb = (wave == 0) ? 0 : (L0 + (wave - 1) * LC);

  float mv[MM];
  float D[32], U[32];

  // ---- replay: evolve mv (all 64 m), store reads ----
  auto replay = [&](int base, int n) {
    float eD[4], aD[4];
#pragma unroll
    for (int j = 0; j < 4; ++j) {
      const int t = base + j;
      const int q = s_q[t];
      const float2 ea = EA[((size_t)(s_r[t] * QD + q)) * VDIM + v];
      eD[j] = ea.x; aD[j] = ea.y;
      s_w[wave][j][lane] = w_tab[(size_t)q * MM + lane];
    }
    const int ng = n >> 2;
    for (int g = 0; g < ng; ++g) {
      const int cb = (g & 1) << 2, nb = ((g + 1) & 1) << 2;
      float eN[4], aN[4];
#pragma unroll
      for (int j = 0; j < 4; ++j) {
        int tp = base + g * 4 + 4 + j; if (tp >= base + n) tp = base + n - 1;
        const int q = s_q[tp];
        const float2 ea = EA[((size_t)(s_r[tp] * QD + q)) * VDIM + v];
        eN[j] = ea.x; aN[j] = ea.y;
        s_w[wave][nb + j][lane] = w_tab[(size_t)q * MM + lane];
      }
#pragma unroll
      for (int j = 0; j < 4; ++j) {
        const float4* w4 = (const float4*)s_w[wave][cb + j];
        const float e = eD[j], a = aD[j];
        float r0 = 0.f, r1 = 0.f, r2 = 0.f, r3 = 0.f;
#pragma unroll
        for (int k = 0; k < 16; ++k) {
          const float4 ww = w4[k];
          float t0;
          r0 = fmaf(ww.x, mv[4 * k + 0], r0);
          t0 = fmaf(-e, mv[4 * k + 0], a); mv[4 * k + 0] = fmaf(ww.x, t0, mv[4 * k + 0]);
          r1 = fmaf(ww.y, mv[4 * k + 1], r1);
          t0 = fmaf(-e, mv[4 * k + 1], a); mv[4 * k + 1] = fmaf(ww.y, t0, mv[4 * k + 1]);
          r2 = fmaf(ww.z, mv[4 * k + 2], r2);
          t0 = fmaf(-e, mv[4 * k + 2], a); mv[4 * k + 2] = fmaf(ww.z, t0, mv[4 * k + 2]);
          r3 = fmaf(ww.w, mv[4 * k + 3], r3);
          t0 = fmaf(-e, mv[4 * k + 3], a); mv[4 * k + 3] = fmaf(ww.w, t0, mv[4 * k + 3]);
        }
        Rd[((size_t)b * SS + base + g * 4 + j) * VDIM + v] = (_Float16)((r0 + r1) + (r2 + r3));
      }
#pragma unroll
      for (int j = 0; j < 4; ++j) { eD[j] = eN[j]; aD[j] = aN[j]; }
    }
  };

  // ---- accum: (D,U) chunk transfer for 32 m's starting at mbase ----
  auto accum = [&](int base, int n, int mbase) {
#pragma unroll
    for (int k = 0; k < 32; ++k) { D[k] = 1.f; U[k] = 0.f; }
    float eD[4], aD[4];
#pragma unroll
    for (int j = 0; j < 4; ++j) {
      const int t = base + j;
      const int q = s_q[t];
      const float2 ea = EA[((size_t)(s_r[t] * QD + q)) * VDIM + v];
      eD[j] = ea.x; aD[j] = ea.y;
      s_w[wave][j][lane] = w_tab[(size_t)q * MM + lane];
    }
    const int ng = n >> 2;
    for (int g = 0; g < ng; ++g) {
      const int cb = (g & 1) << 2, nb = ((g + 1) & 1) << 2;
      float eN[4], aN[4];
#pragma unroll
      for (int j = 0; j < 4; ++j) {
        int tp = base + g * 4 + 4 + j; if (tp >= base + n) tp = base + n - 1;
        const int q = s_q[tp];
        const float2 ea = EA[((size_t)(s_r[tp] * QD + q)) * VDIM + v];
        eN[j] = ea.x; aN[j] = ea.y;
        s_w[wave][nb + j][lane] = w_tab[(size_t)q * MM + lane];
      }
#pragma unroll
      for (int j = 0; j < 4; ++j) {
        const float4* w4 = (const float4*)(s_w[wave][cb + j] + mbase);
        const float e = eD[j], a = aD[j];
#pragma unroll
        for (int k = 0; k < 8; ++k) {
          const float4 ww = w4[k];
          float c;
          c = ww.x * e; D[4 * k + 0] = fmaf(-c, D[4 * k + 0], D[4 * k + 0]);
          U[4 * k + 0] = fmaf(-c, U[4 * k + 0], U[4 * k + 0]); U[4 * k + 0] = fmaf(ww.x, a, U[4 * k + 0]);
          c = ww.y * e; D[4 * k + 1] = fmaf(-c, D[4 * k + 1], D[4 * k + 1]);
          U[4 * k + 1] = fmaf(-c, U[4 * k + 1], U[4 * k + 1]); U[4 * k + 1] = fmaf(ww.y, a, U[4 * k + 1]);
          c = ww.z * e; D[4 * k + 2] = fmaf(-c, D[4 * k + 2], D[4 * k + 2]);
          U[4 * k + 2] = fmaf(-c, U[4 * k + 2], U[4 * k + 2]); U[4 * k + 2] = fmaf(ww.z, a, U[4 * k + 2]);
          c = ww.w * e; D[4 * k + 3] = fmaf(-c, D[4 * k + 3], D[4 * k + 3]);
          U[4 * k + 3] = fmaf(-c, U[4 * k + 3], U[4 * k + 3]); U[4 * k + 3] = fmaf(ww.w, a, U[4 * k + 3]);
        }
      }
#pragma unroll
      for (int j = 0; j < 4; ++j) { eD[j] = eN[j]; aD[j] = aN[j]; }
    }
  };

  // ---- phase 1: wave0 replay + publish boundary; waves>0 accum half A ----
  if (wave == 0) {
#pragma unroll
    for (int m = 0; m < MM; ++m) mv[m] = init_mv[m * VDIM + v];
    replay(0, L0);
#pragma unroll
    for (int m = 0; m < MM; ++m) s_R[m * 64 + lane] = mv[m];
  } else {
    accum(tb, LC, 0);
  }
  __syncthreads();

  // ---- scan A: propagate boundaries for m in [0,32) ----
  for (int rr = 1; rr < 8; ++rr) {
    if (wave == rr) {
#pragma unroll
      for (int k = 0; k < 32; ++k) {
        const float x = s_R[k * 64 + lane];
        s_R[k * 64 + lane] = fmaf(x, D[k], U[k]);
        mv[k] = x;
      }
    }
    __syncthreads();
  }

  // ---- phase 1B: accum half B ----
  if (wave > 0) accum(tb, LC, 32);
  __syncthreads();

  // ---- scan B: propagate boundaries for m in [32,64) ----
  for (int rr = 1; rr < 8; ++rr) {
    if (wave == rr) {
#pragma unroll
      for (int k = 0; k < 32; ++k) {
        const float x = s_R[(32 + k) * 64 + lane];
        s_R[(32 + k) * 64 + lane] = fmaf(x, D[k], U[k]);
        mv[32 + k] = x;
      }
    }
    __syncthreads();
  }

  // ---- phase 3: replay chunks 1..7 from boundary states ----
  if (wave > 0) replay(tb, LC);
}

// ---------------- K4: parallel summary GEMM + heads + CORAL over all (b,t) ----------------
__global__ __launch_bounds__(256) void k_head(
    const int* __restrict__ q_data,
    const _Float16* __restrict__ Rd, const _Float16* __restrict__ Wh,
    const float* __restrict__ Sq_tab, const float* __restrict__ aq_tab,
    const float* __restrict__ beta_tab,
    const float* __restrict__ W_theta, const float* __restrict__ b_theta,
    const float* __restrict__ W_disc, const float* __restrict__ b_disc,
    const float* __restrict__ W_c1, const float* __restrict__ b_c1,
    const float* __restrict__ W_c2, const float* __restrict__ b_c2,
    const float* __restrict__ coral_w, const float* __restrict__ coral_b,
    float* __restrict__ out)
{
  const int tid = threadIdx.x;
  const int w = tid >> 6, l = tid & 63;
  const int rowbase = blockIdx.x * 64;           // 64 rows (same b: 64 | 1024)
  const int b = rowbase >> 10;
  const int t0 = rowbase & (SS - 1);

  __shared__ __align__(16) _Float16 s_A[64 * 256];   // 32 KB
  __shared__ __align__(16) _Float16 s_sum[64 * 128]; // 16 KB
  __shared__ int   s_q[64];
  __shared__ float s_aq[64];
  __shared__ float s_be[64][3];

  {
    const uint4* src = (const uint4*)(Rd + (size_t)rowbase * VDIM);
    uint4* dst = (uint4*)s_A;
    for (int i = tid; i < (64 * 256 * 2) / 16; i += 256) dst[i] = src[i];
  }
  if (tid < 64) {
    const int q = q_data[b * SS + t0 + tid];
    s_q[tid] = q;
    s_aq[tid] = aq_tab[q];
    s_be[tid][0] = beta_tab[(size_t)q * 3 + 0];
    s_be[tid][1] = beta_tab[(size_t)q * 3 + 1];
    s_be[tid][2] = beta_tab[(size_t)q * 3 + 2];
  }

  const int fp = l >> 1, g = l & 1;
  const int fbase = (w & 1) * 64;
  const int f0 = fbase + 2 * fp, f1 = f0 + 1;
  U4 wr0[16], wr1[16];
  {
    const uint4* p0 = (const uint4*)(Wh + (size_t)f0 * 256 + g * 128);
    const uint4* p1 = (const uint4*)(Wh + (size_t)f1 * 256 + g * 128);
#pragma unroll
    for (int i = 0; i < 16; ++i) { wr0[i].u = p0[i]; wr1[i].u = p1[i]; }
  }
  __syncthreads();

  for (int rp = 0; rp < 32; ++rp) {
    const int r = 2 * rp + (w >> 1);
    const uint4* a4 = (const uint4*)(s_A + r * 256 + g * 128);
    float a0 = 0.f, a1 = 0.f, c0 = 0.f, c1 = 0.f;
#pragma unroll
    for (int i = 0; i < 16; i += 2) {
      U4 x; x.u = a4[i];
      U4 y; y.u = a4[i + 1];
#pragma unroll
      for (int j = 0; j < 4; ++j) {
        a0 = dot2_(x.h[j], wr0[i].h[j], a0);
        a1 = dot2_(x.h[j], wr1[i].h[j], a1);
        c0 = dot2_(y.h[j], wr0[i + 1].h[j], c0);
        c1 = dot2_(y.h[j], wr1[i + 1].h[j], c1);
      }
    }
    float f0acc = a0 + c0, f1acc = a1 + c1;
    f0acc += __shfl_xor(f0acc, 1);
    f1acc += __shfl_xor(f1acc, 1);
    if (g == 0) {
      const float2 sq = *(const float2*)(Sq_tab + (size_t)s_q[r] * FDIM + f0);
      s_sum[r * 128 + f0] = (_Float16)tanhf(f0acc + sq.x);
      s_sum[r * 128 + f1] = (_Float16)tanhf(f1acc + sq.y);
    }
  }
  __syncthreads();

  const float tw0 = W_theta[l], tw1 = W_theta[64 + l], tb = b_theta[0];
  const float dw0 = W_disc[l], dw1 = W_disc[64 + l], db = b_disc[0];
  float wc1reg[5];
#pragma unroll
  for (int i = 0; i < 5; ++i) wc1reg[i] = W_c1[i * 64 + l];
  const float bc1 = b_c1[l];
  const int jj = l >> 1, hh2 = l & 1;
  float wc2reg[32];
#pragma unroll
  for (int i = 0; i < 32; ++i) wc2reg[i] = W_c2[(hh2 * 32 + i) * 32 + jj];
  const float bc2 = b_c2[jj];
  const float cw = coral_w[jj];
  const float cb0 = coral_b[0], cb1 = coral_b[1], cb2 = coral_b[2];

  float* out_theta = out;
  float* out_beta  = out + (size_t)BB * SS;
  float* out_alpha = out + (size_t)BB * SS * 4;
  float* out_probs = out + (size_t)BB * SS * 5;
  float* out_logit = out + (size_t)BB * SS * 9;

  for (int rr = 0; rr < 16; ++rr) {
    const int r = w * 16 + rr;
    const float su0 = (float)s_sum[r * 128 + l];
    const float su1 = (float)s_sum[r * 128 + 64 + l];
    float at = su0 * tw0 + su1 * tw1;
    float ad = su0 * dw0 + su1 * dw1;
#pragma unroll
    for (int o = 32; o; o >>= 1) { at += __shfl_xor(at, o); ad += __shfl_xor(ad, o); }
    const float theta = (at + tb) * 3.0f;
    const float alpha = softplusf_(ad + s_aq[r] + db);
    const float be0 = s_be[r][0], be1 = s_be[r][1], be2 = s_be[r][2];
    float h1 = bc1;
    h1 = fmaf(theta, wc1reg[0], h1);
    h1 = fmaf(alpha, wc1reg[1], h1);
    h1 = fmaf(be0, wc1reg[2], h1);
    h1 = fmaf(be1, wc1reg[3], h1);
    h1 = fmaf(be2, wc1reg[4], h1);
    h1 = fmaxf(h1, 0.f);
    float hacc = hh2 ? 0.f : bc2;
#pragma unroll
    for (int i = 0; i < 32; ++i)
      hacc = fmaf(__shfl(h1, hh2 * 32 + i), wc2reg[i], hacc);
    hacc += __shfl_xor(hacc, 1);
    const float h2 = fmaxf(hacc, 0.f);
    float p = h2 * cw * 0.5f;
#pragma unroll
    for (int o = 32; o; o >>= 1) p += __shfl_xor(p, o);
    if (l == 0) {
      const float z = p;
      const float l0 = z + cb0, l1 = z + cb1, l2 = z + cb2;
      const float s0 = sigmoidf_(l0), s1 = sigmoidf_(l1), s2 = sigmoidf_(l2);
      const float q0 = s0, q1 = s0 * s1, q2 = s0 * s1 * s2;
      const size_t bt = (size_t)rowbase + r;
      out_theta[bt] = theta;
      out_alpha[bt] = alpha;
      out_beta[bt * 3 + 0] = be0;
      out_beta[bt * 3 + 1] = be1;
      out_beta[bt * 3 + 2] = be2;
      out_logit[bt * 3 + 0] = l0;
      out_logit[bt * 3 + 1] = l1;
      out_logit[bt * 3 + 2] = l2;
      out_probs[bt * 4 + 0] = 1.f - q0;
      out_probs[bt * 4 + 1] = q0 - q1;
      out_probs[bt * 4 + 2] = q1 - q2;
      out_probs[bt * 4 + 3] = q2;
    }
  }
}

extern "C" void kernel_launch(void* const* d_in, const int* in_sizes, int n_in,
                              void* d_out, int out_size, void* d_ws, size_t ws_size,
                              hipStream_t stream) {
  const int*   q_data    = (const int*)d_in[0];
  const int*   r_data    = (const int*)d_in[1];
  const float* q_embed   = (const float*)d_in[2];
  const float* key_mem   = (const float*)d_in[3];
  const float* init_mv   = (const float*)d_in[4];
  const float* W_value   = (const float*)d_in[5];
  const float* b_value   = (const float*)d_in[6];
  const float* W_erase   = (const float*)d_in[7];
  const float* b_erase   = (const float*)d_in[8];
  const float* W_add     = (const float*)d_in[9];
  const float* b_add     = (const float*)d_in[10];
  const float* W_summary = (const float*)d_in[11];
  const float* b_summary = (const float*)d_in[12];
  const float* W_theta   = (const float*)d_in[13];
  const float* b_theta   = (const float*)d_in[14];
  const float* W_beta    = (const float*)d_in[15];
  const float* b_beta    = (const float*)d_in[16];
  const float* W_disc    = (const float*)d_in[17];
  const float* b_disc    = (const float*)d_in[18];
  const float* W_c1      = (const float*)d_in[19];
  const float* b_c1      = (const float*)d_in[20];
  const float* W_c2      = (const float*)d_in[21];
  const float* b_c2      = (const float*)d_in[22];
  const float* coral_w   = (const float*)d_in[23];
  const float* coral_b   = (const float*)d_in[24];

  float* ws = (float*)d_ws;
  size_t off = 0;
  float2* EA      = (float2*)(ws + off); off += (size_t)RROWS * VDIM * 2;  // 10,242,048 floats
  float* w_tab    = ws + off; off += (size_t)QD * MM;
  float* Sq_tab   = ws + off; off += (size_t)QD * FDIM;
  float* aq_tab   = ws + off; off += 5120;
  float* beta_tab = ws + off; off += 15104;
  _Float16* Wh = (_Float16*)(ws + off); off += (VDIM * FDIM) / 2;
  _Float16* Rd = (_Float16*)(ws + off);

  k_prep<<<dim3(128), dim3(256), 0, stream>>>(W_summary, Wh);

  k_ea<<<dim3((RROWS + 31) / 32), dim3(256), 0, stream>>>(
      W_value, b_value, W_erase, b_erase, W_add, b_add, EA);

  k_q<<<dim3(QD), dim3(256), 0, stream>>>(
      q_embed, key_mem, W_summary, b_summary, W_disc, W_beta, b_beta,
      w_tab, Sq_tab, aq_tab, beta_tab);

  k_rec3<<<dim3(BB * 4), dim3(512), 0, stream>>>(
      q_data, r_data, init_mv, EA, w_tab, Rd);

  k_head<<<dim3((BB * SS) / 64), dim3(256), 0, stream>>>(
      q_data, Rd, Wh, Sq_tab, aq_tab, beta_tab,
      W_theta, b_theta, W_disc, b_disc,
      W_c1, b_c1, W_c2, b_c2, coral_w, coral_b, (float*)d_out);
}

// Round 6
// 989.384 us; speedup vs baseline: 1.1525x; 1.0663x over previous
//
#include <hip/hip_runtime.h>
#include <math.h>

#define BB 128
#define SS 1024
#define MM 64
#define KDIM 128
#define VDIM 256
#define FDIM 128
#define QNUM 5000
#define QD 5001            // q ids 0..5000
#define RROWS (4 * QD)     // 20004 distinct (r,q) rows

#define L0 100             // wave-0 chunk (replay-only)
#define LC 132             // waves 1..7 chunk (accum A+B then replay)
#define MA 40              // m-split: pass A covers m [0,40)
#define MB 24              // pass B covers m [40,64)

typedef _Float16 half2_t __attribute__((ext_vector_type(2)));
union U4 { uint4 u; half2_t h[4]; };

#if defined(__has_builtin)
#if __has_builtin(__builtin_amdgcn_fdot2)
#define HAVE_FDOT2 1
#endif
#endif

__device__ __forceinline__ float dot2_(half2_t a, half2_t b, float c) {
#ifdef HAVE_FDOT2
  return __builtin_amdgcn_fdot2(a, b, c, false);
#else
  return c + (float)a[0] * (float)b[0] + (float)a[1] * (float)b[1];
#endif
}

__device__ __forceinline__ float sigmoidf_(float x) { return 1.0f / (1.0f + expf(-x)); }
__device__ __forceinline__ float softplusf_(float x) { return (x > 20.0f) ? x : log1pf(expf(x)); }

// ---------------- K0: W_summary read-part -> f16, [f][k] layout ----------------
__global__ __launch_bounds__(256) void k_prep(const float* __restrict__ W_summary,
                                              _Float16* __restrict__ Wh)
{
  const int e = blockIdx.x * 256 + threadIdx.x;   // 0..32767
  const int f = e >> 8, k = e & 255;
  Wh[(size_t)f * 256 + k] = (_Float16)W_summary[(size_t)k * FDIM + f];
}

// ---------------- K1: E/A table over all (r,q): 20004 rows, packed float2 ----------------
__global__ __launch_bounds__(256) void k_ea(
    const float* __restrict__ Wv, const float* __restrict__ bv,
    const float* __restrict__ We, const float* __restrict__ be,
    const float* __restrict__ Wa, const float* __restrict__ ba,
    float2* __restrict__ EA)
{
  const int tid = threadIdx.x;
  const int base = blockIdx.x * 32;
  __shared__ float sve[32][256];
#pragma unroll
  for (int j = 0; j < 32; ++j) {
    const int rr = base + j;
    float v = bv[tid];
    if (rr < RROWS) {
      const int q = rr % QD;
      const int r = rr / QD;
      if (q >= 1) {
        const float sc = (float)r * (1.0f / 3.0f);
        v += Wv[(size_t)(q - 1) * VDIM + tid] + sc * Wv[(size_t)(QNUM + q - 1) * VDIM + tid];
      }
    }
    sve[j][tid] = v;
  }
  __syncthreads();
  float ea[32], aa[32];
#pragma unroll
  for (int j = 0; j < 32; ++j) { ea[j] = 0.f; aa[j] = 0.f; }
#pragma unroll 4
  for (int i = 0; i < 256; ++i) {
    const float we = We[i * VDIM + tid];
    const float wa = Wa[i * VDIM + tid];
#pragma unroll
    for (int j = 0; j < 32; ++j) {
      ea[j] = fmaf(sve[j][i], we, ea[j]);
      aa[j] = fmaf(sve[j][i], wa, aa[j]);
    }
  }
  const float bev = be[tid], bav = ba[tid];
#pragma unroll
  for (int j = 0; j < 32; ++j) {
    const int rr = base + j;
    if (rr < RROWS) {
      float2 p;
      p.x = sigmoidf_(ea[j] + bev);
      p.y = tanhf(aa[j] + bav);
      EA[(size_t)rr * VDIM + tid] = p;
    }
  }
}

// ---------------- K2: per-q tables: w (softmax), Sq, aq, betas ----------------
__global__ __launch_bounds__(256) void k_q(
    const float* __restrict__ q_embed, const float* __restrict__ key_mem,
    const float* __restrict__ W_summary, const float* __restrict__ b_summary,
    const float* __restrict__ W_disc,
    const float* __restrict__ W_beta, const float* __restrict__ b_beta,
    float* __restrict__ w_tab, float* __restrict__ Sq_tab,
    float* __restrict__ aq_tab, float* __restrict__ beta_tab)
{
  const int q = blockIdx.x;
  const int tid = threadIdx.x;
  const int wave = tid >> 6, l = tid & 63;
  __shared__ float qe[KDIM];
  __shared__ float slog[MM];
  if (tid < KDIM) qe[tid] = q_embed[(size_t)q * KDIM + tid];
  __syncthreads();
  {
    const int m = tid >> 2, j = tid & 3;
    const float* krow = key_mem + m * KDIM + j * 32;
    const float* qrow = qe + j * 32;
    float acc = 0.f;
#pragma unroll
    for (int k = 0; k < 32; ++k) {
      const int i = (k + tid) & 31;
      acc = fmaf(qrow[i], krow[i], acc);
    }
    acc += __shfl_xor(acc, 1);
    acc += __shfl_xor(acc, 2);
    if (j == 0) slog[m] = acc;
  }
  __syncthreads();
  if (wave == 0) {
    const float x = slog[l];
    float mx = x;
#pragma unroll
    for (int o = 32; o; o >>= 1) mx = fmaxf(mx, __shfl_xor(mx, o));
    const float e = expf(x - mx);
    float s = e;
#pragma unroll
    for (int o = 32; o; o >>= 1) s += __shfl_xor(s, o);
    w_tab[(size_t)q * MM + l] = e / s;
  } else if (wave == 1) {
    float p = qe[l] * W_disc[KDIM + l] + qe[64 + l] * W_disc[KDIM + 64 + l];
#pragma unroll
    for (int o = 32; o; o >>= 1) p += __shfl_xor(p, o);
    if (l == 0) aq_tab[q] = p;
  } else if (wave == 2) {
    float p0 = qe[l] * W_beta[l * 3 + 0] + qe[64 + l] * W_beta[(64 + l) * 3 + 0];
    float p1 = qe[l] * W_beta[l * 3 + 1] + qe[64 + l] * W_beta[(64 + l) * 3 + 1];
    float p2 = qe[l] * W_beta[l * 3 + 2] + qe[64 + l] * W_beta[(64 + l) * 3 + 2];
#pragma unroll
    for (int o = 32; o; o >>= 1) {
      p0 += __shfl_xor(p0, o); p1 += __shfl_xor(p1, o); p2 += __shfl_xor(p2, o);
    }
    if (l == 0) {
      beta_tab[(size_t)q * 3 + 0] = p0 + b_beta[0];
      beta_tab[(size_t)q * 3 + 1] = p1 + b_beta[1];
      beta_tab[(size_t)q * 3 + 2] = p2 + b_beta[2];
    }
  }
  {
    const int f = tid >> 1, h = tid & 1;
    float acc = 0.f;
#pragma unroll 8
    for (int ii = 0; ii < 64; ++ii)
      acc = fmaf(qe[h * 64 + ii], W_summary[(size_t)(VDIM + h * 64 + ii) * FDIM + f], acc);
    acc += __shfl_xor(acc, 1);
    if (h == 0) Sq_tab[(size_t)q * FDIM + f] = acc + b_summary[f];
  }
}

// ---------------- K3: chunked scan, 40/24 m-split (no spills), balanced phases ----------------
__global__ __launch_bounds__(512, 2) void k_rec4(
    const int* __restrict__ q_data, const int* __restrict__ r_data,
    const float* __restrict__ init_mv,
    const float2* __restrict__ EA, const float* __restrict__ w_tab,
    _Float16* __restrict__ Rd)
{
  const int tid = threadIdx.x;
  const int wave = tid >> 6, lane = tid & 63;
  const int b = blockIdx.x >> 2, vc = blockIdx.x & 3;
  const int v = vc * 64 + lane;

  __shared__ int s_q[SS];
  __shared__ int s_r[SS];
  __shared__ __align__(16) float s_w[8][8][MM];   // per-wave ring (wave-synchronous)
  __shared__ float s_R[MM * 64];                  // running boundary state [m][lane]

  for (int i = tid; i < SS; i += 512) {
    s_q[i] = q_data[b * SS + i];
    s_r[i] = r_data[b * SS + i];
  }
  __syncthreads();

  const int tb = (wave == 0) ? 0 : (L0 + (wave - 1) * LC);

  float mv[MM];
  float D[MA], U[MA];

  // ---- replay: evolve mv (all 64 m), store reads ----
  auto replay = [&](int base, int n) {
    float eD[4], aD[4];
#pragma unroll
    for (int j = 0; j < 4; ++j) {
      const int t = base + j;
      const int q = s_q[t];
      const float2 ea = EA[((size_t)(s_r[t] * QD + q)) * VDIM + v];
      eD[j] = ea.x; aD[j] = ea.y;
      s_w[wave][j][lane] = w_tab[(size_t)q * MM + lane];
    }
    const int ng = n >> 2;
    for (int g = 0; g < ng; ++g) {
      const int cb = (g & 1) << 2, nb = ((g + 1) & 1) << 2;
      float eN[4], aN[4];
#pragma unroll
      for (int j = 0; j < 4; ++j) {
        int tp = base + g * 4 + 4 + j; if (tp >= base + n) tp = base + n - 1;
        const int q = s_q[tp];
        const float2 ea = EA[((size_t)(s_r[tp] * QD + q)) * VDIM + v];
        eN[j] = ea.x; aN[j] = ea.y;
        s_w[wave][nb + j][lane] = w_tab[(size_t)q * MM + lane];
      }
#pragma unroll
      for (int j = 0; j < 4; ++j) {
        const float4* w4 = (const float4*)s_w[wave][cb + j];
        const float e = eD[j], a = aD[j];
        float r0 = 0.f, r1 = 0.f, r2 = 0.f, r3 = 0.f;
#pragma unroll
        for (int k = 0; k < 16; ++k) {
          const float4 ww = w4[k];
          float t0;
          r0 = fmaf(ww.x, mv[4 * k + 0], r0);
          t0 = fmaf(-e, mv[4 * k + 0], a); mv[4 * k + 0] = fmaf(ww.x, t0, mv[4 * k + 0]);
          r1 = fmaf(ww.y, mv[4 * k + 1], r1);
          t0 = fmaf(-e, mv[4 * k + 1], a); mv[4 * k + 1] = fmaf(ww.y, t0, mv[4 * k + 1]);
          r2 = fmaf(ww.z, mv[4 * k + 2], r2);
          t0 = fmaf(-e, mv[4 * k + 2], a); mv[4 * k + 2] = fmaf(ww.z, t0, mv[4 * k + 2]);
          r3 = fmaf(ww.w, mv[4 * k + 3], r3);
          t0 = fmaf(-e, mv[4 * k + 3], a); mv[4 * k + 3] = fmaf(ww.w, t0, mv[4 * k + 3]);
        }
        Rd[((size_t)b * SS + base + g * 4 + j) * VDIM + v] = (_Float16)((r0 + r1) + (r2 + r3));
      }
#pragma unroll
      for (int j = 0; j < 4; ++j) { eD[j] = eN[j]; aD[j] = aN[j]; }
    }
  };

  // ---- accum pass A: (D,U) for m in [0,MA) ----
  auto accumA = [&](int base, int n) {
#pragma unroll
    for (int k = 0; k < MA; ++k) { D[k] = 1.f; U[k] = 0.f; }
    float eD[4], aD[4];
#pragma unroll
    for (int j = 0; j < 4; ++j) {
      const int t = base + j;
      const int q = s_q[t];
      const float2 ea = EA[((size_t)(s_r[t] * QD + q)) * VDIM + v];
      eD[j] = ea.x; aD[j] = ea.y;
      s_w[wave][j][lane] = w_tab[(size_t)q * MM + lane];
    }
    const int ng = n >> 2;
    for (int g = 0; g < ng; ++g) {
      const int cb = (g & 1) << 2, nb = ((g + 1) & 1) << 2;
      float eN[4], aN[4];
#pragma unroll
      for (int j = 0; j < 4; ++j) {
        int tp = base + g * 4 + 4 + j; if (tp >= base + n) tp = base + n - 1;
        const int q = s_q[tp];
        const float2 ea = EA[((size_t)(s_r[tp] * QD + q)) * VDIM + v];
        eN[j] = ea.x; aN[j] = ea.y;
        s_w[wave][nb + j][lane] = w_tab[(size_t)q * MM + lane];
      }
#pragma unroll
      for (int j = 0; j < 4; ++j) {
        const float4* w4 = (const float4*)s_w[wave][cb + j];
        const float e = eD[j], a = aD[j];
#pragma unroll
        for (int k = 0; k < MA / 4; ++k) {
          const float4 ww = w4[k];
          float c;
          c = ww.x * e; D[4 * k + 0] = fmaf(-c, D[4 * k + 0], D[4 * k + 0]);
          U[4 * k + 0] = fmaf(-c, U[4 * k + 0], U[4 * k + 0]); U[4 * k + 0] = fmaf(ww.x, a, U[4 * k + 0]);
          c = ww.y * e; D[4 * k + 1] = fmaf(-c, D[4 * k + 1], D[4 * k + 1]);
          U[4 * k + 1] = fmaf(-c, U[4 * k + 1], U[4 * k + 1]); U[4 * k + 1] = fmaf(ww.y, a, U[4 * k + 1]);
          c = ww.z * e; D[4 * k + 2] = fmaf(-c, D[4 * k + 2], D[4 * k + 2]);
          U[4 * k + 2] = fmaf(-c, U[4 * k + 2], U[4 * k + 2]); U[4 * k + 2] = fmaf(ww.z, a, U[4 * k + 2]);
          c = ww.w * e; D[4 * k + 3] = fmaf(-c, D[4 * k + 3], D[4 * k + 3]);
          U[4 * k + 3] = fmaf(-c, U[4 * k + 3], U[4 * k + 3]); U[4 * k + 3] = fmaf(ww.w, a, U[4 * k + 3]);
        }
      }
#pragma unroll
      for (int j = 0; j < 4; ++j) { eD[j] = eN[j]; aD[j] = aN[j]; }
    }
  };

  // ---- accum pass B: (D,U) for m in [MA,64) — only MB regs of D/U live, mv[0:MA] held ----
  auto accumB = [&](int base, int n) {
#pragma unroll
    for (int k = 0; k < MB; ++k) { D[k] = 1.f; U[k] = 0.f; }
    float eD[4], aD[4];
#pragma unroll
    for (int j = 0; j < 4; ++j) {
      const int t = base + j;
      const int q = s_q[t];
      const float2 ea = EA[((size_t)(s_r[t] * QD + q)) * VDIM + v];
      eD[j] = ea.x; aD[j] = ea.y;
      s_w[wave][j][lane] = w_tab[(size_t)q * MM + lane];
    }
    const int ng = n >> 2;
    for (int g = 0; g < ng; ++g) {
      const int cb = (g & 1) << 2, nb = ((g + 1) & 1) << 2;
      float eN[4], aN[4];
#pragma unroll
      for (int j = 0; j < 4; ++j) {
        int tp = base + g * 4 + 4 + j; if (tp >= base + n) tp = base + n - 1;
        const int q = s_q[tp];
        const float2 ea = EA[((size_t)(s_r[tp] * QD + q)) * VDIM + v];
        eN[j] = ea.x; aN[j] = ea.y;
        s_w[wave][nb + j][lane] = w_tab[(size_t)q * MM + lane];
      }
#pragma unroll
      for (int j = 0; j < 4; ++j) {
        const float4* w4 = (const float4*)(s_w[wave][cb + j] + MA);
        const float e = eD[j], a = aD[j];
#pragma unroll
        for (int k = 0; k < MB / 4; ++k) {
          const float4 ww = w4[k];
          float c;
          c = ww.x * e; D[4 * k + 0] = fmaf(-c, D[4 * k + 0], D[4 * k + 0]);
          U[4 * k + 0] = fmaf(-c, U[4 * k + 0], U[4 * k + 0]); U[4 * k + 0] = fmaf(ww.x, a, U[4 * k + 0]);
          c = ww.y * e; D[4 * k + 1] = fmaf(-c, D[4 * k + 1], D[4 * k + 1]);
          U[4 * k + 1] = fmaf(-c, U[4 * k + 1], U[4 * k + 1]); U[4 * k + 1] = fmaf(ww.y, a, U[4 * k + 1]);
          c = ww.z * e; D[4 * k + 2] = fmaf(-c, D[4 * k + 2], D[4 * k + 2]);
          U[4 * k + 2] = fmaf(-c, U[4 * k + 2], U[4 * k + 2]); U[4 * k + 2] = fmaf(ww.z, a, U[4 * k + 2]);
          c = ww.w * e; D[4 * k + 3] = fmaf(-c, D[4 * k + 3], D[4 * k + 3]);
          U[4 * k + 3] = fmaf(-c, U[4 * k + 3], U[4 * k + 3]); U[4 * k + 3] = fmaf(ww.w, a, U[4 * k + 3]);
        }
      }
#pragma unroll
      for (int j = 0; j < 4; ++j) { eD[j] = eN[j]; aD[j] = aN[j]; }
    }
  };

  // ---- phase 1: wave0 replay + publish boundary; waves>0 accum pass A ----
  if (wave == 0) {
#pragma unroll
    for (int m = 0; m < MM; ++m) mv[m] = init_mv[m * VDIM + v];
    replay(0, L0);
#pragma unroll
    for (int m = 0; m < MM; ++m) s_R[m * 64 + lane] = mv[m];
  } else {
    accumA(tb, LC);
  }
  __syncthreads();

  // ---- scan A: propagate boundaries for m in [0,MA) ----
  for (int rr = 1; rr < 8; ++rr) {
    if (wave == rr) {
#pragma unroll
      for (int k = 0; k < MA; ++k) {
        const float x = s_R[k * 64 + lane];
        s_R[k * 64 + lane] = fmaf(x, D[k], U[k]);
        mv[k] = x;
      }
    }
    __syncthreads();
  }

  // ---- phase 1B: accum pass B ----
  if (wave > 0) accumB(tb, LC);
  __syncthreads();

  // ---- scan B: propagate boundaries for m in [MA,64) ----
  for (int rr = 1; rr < 8; ++rr) {
    if (wave == rr) {
#pragma unroll
      for (int k = 0; k < MB; ++k) {
        const float x = s_R[(MA + k) * 64 + lane];
        s_R[(MA + k) * 64 + lane] = fmaf(x, D[k], U[k]);
        mv[MA + k] = x;
      }
    }
    __syncthreads();
  }

  // ---- phase 3: replay chunks 1..7 from boundary states ----
  if (wave > 0) replay(tb, LC);
}

// ---------------- K4: parallel summary GEMM + heads + CORAL over all (b,t) ----------------
__global__ __launch_bounds__(256) void k_head(
    const int* __restrict__ q_data,
    const _Float16* __restrict__ Rd, const _Float16* __restrict__ Wh,
    const float* __restrict__ Sq_tab, const float* __restrict__ aq_tab,
    const float* __restrict__ beta_tab,
    const float* __restrict__ W_theta, const float* __restrict__ b_theta,
    const float* __restrict__ W_disc, const float* __restrict__ b_disc,
    const float* __restrict__ W_c1, const float* __restrict__ b_c1,
    const float* __restrict__ W_c2, const float* __restrict__ b_c2,
    const float* __restrict__ coral_w, const float* __restrict__ coral_b,
    float* __restrict__ out)
{
  const int tid = threadIdx.x;
  const int w = tid >> 6, l = tid & 63;
  const int rowbase = blockIdx.x * 64;           // 64 rows (same b: 64 | 1024)
  const int b = rowbase >> 10;
  const int t0 = rowbase & (SS - 1);

  __shared__ __align__(16) _Float16 s_A[64 * 256];   // 32 KB
  __shared__ __align__(16) _Float16 s_sum[64 * 128]; // 16 KB
  __shared__ int   s_q[64];
  __shared__ float s_aq[64];
  __shared__ float s_be[64][3];

  {
    const uint4* src = (const uint4*)(Rd + (size_t)rowbase * VDIM);
    uint4* dst = (uint4*)s_A;
    for (int i = tid; i < (64 * 256 * 2) / 16; i += 256) dst[i] = src[i];
  }
  if (tid < 64) {
    const int q = q_data[b * SS + t0 + tid];
    s_q[tid] = q;
    s_aq[tid] = aq_tab[q];
    s_be[tid][0] = beta_tab[(size_t)q * 3 + 0];
    s_be[tid][1] = beta_tab[(size_t)q * 3 + 1];
    s_be[tid][2] = beta_tab[(size_t)q * 3 + 2];
  }

  const int fp = l >> 1, g = l & 1;
  const int fbase = (w & 1) * 64;
  const int f0 = fbase + 2 * fp, f1 = f0 + 1;
  U4 wr0[16], wr1[16];
  {
    const uint4* p0 = (const uint4*)(Wh + (size_t)f0 * 256 + g * 128);
    const uint4* p1 = (const uint4*)(Wh + (size_t)f1 * 256 + g * 128);
#pragma unroll
    for (int i = 0; i < 16; ++i) { wr0[i].u = p0[i]; wr1[i].u = p1[i]; }
  }
  __syncthreads();

  for (int rp = 0; rp < 32; ++rp) {
    const int r = 2 * rp + (w >> 1);
    const uint4* a4 = (const uint4*)(s_A + r * 256 + g * 128);
    float a0 = 0.f, a1 = 0.f, c0 = 0.f, c1 = 0.f;
#pragma unroll
    for (int i = 0; i < 16; i += 2) {
      U4 x; x.u = a4[i];
      U4 y; y.u = a4[i + 1];
#pragma unroll
      for (int j = 0; j < 4; ++j) {
        a0 = dot2_(x.h[j], wr0[i].h[j], a0);
        a1 = dot2_(x.h[j], wr1[i].h[j], a1);
        c0 = dot2_(y.h[j], wr0[i + 1].h[j], c0);
        c1 = dot2_(y.h[j], wr1[i + 1].h[j], c1);
      }
    }
    float f0acc = a0 + c0, f1acc = a1 + c1;
    f0acc += __shfl_xor(f0acc, 1);
    f1acc += __shfl_xor(f1acc, 1);
    if (g == 0) {
      const float2 sq = *(const float2*)(Sq_tab + (size_t)s_q[r] * FDIM + f0);
      s_sum[r * 128 + f0] = (_Float16)tanhf(f0acc + sq.x);
      s_sum[r * 128 + f1] = (_Float16)tanhf(f1acc + sq.y);
    }
  }
  __syncthreads();

  const float tw0 = W_theta[l], tw1 = W_theta[64 + l], tb = b_theta[0];
  const float dw0 = W_disc[l], dw1 = W_disc[64 + l], db = b_disc[0];
  float wc1reg[5];
#pragma unroll
  for (int i = 0; i < 5; ++i) wc1reg[i] = W_c1[i * 64 + l];
  const float bc1 = b_c1[l];
  const int jj = l >> 1, hh2 = l & 1;
  float wc2reg[32];
#pragma unroll
  for (int i = 0; i < 32; ++i) wc2reg[i] = W_c2[(hh2 * 32 + i) * 32 + jj];
  const float bc2 = b_c2[jj];
  const float cw = coral_w[jj];
  const float cb0 = coral_b[0], cb1 = coral_b[1], cb2 = coral_b[2];

  float* out_theta = out;
  float* out_beta  = out + (size_t)BB * SS;
  float* out_alpha = out + (size_t)BB * SS * 4;
  float* out_probs = out + (size_t)BB * SS * 5;
  float* out_logit = out + (size_t)BB * SS * 9;

  for (int rr = 0; rr < 16; ++rr) {
    const int r = w * 16 + rr;
    const float su0 = (float)s_sum[r * 128 + l];
    const float su1 = (float)s_sum[r * 128 + 64 + l];
    float at = su0 * tw0 + su1 * tw1;
    float ad = su0 * dw0 + su1 * dw1;
#pragma unroll
    for (int o = 32; o; o >>= 1) { at += __shfl_xor(at, o); ad += __shfl_xor(ad, o); }
    const float theta = (at + tb) * 3.0f;
    const float alpha = softplusf_(ad + s_aq[r] + db);
    const float be0 = s_be[r][0], be1 = s_be[r][1], be2 = s_be[r][2];
    float h1 = bc1;
    h1 = fmaf(theta, wc1reg[0], h1);
    h1 = fmaf(alpha, wc1reg[1], h1);
    h1 = fmaf(be0, wc1reg[2], h1);
    h1 = fmaf(be1, wc1reg[3], h1);
    h1 = fmaf(be2, wc1reg[4], h1);
    h1 = fmaxf(h1, 0.f);
    float hacc = hh2 ? 0.f : bc2;
#pragma unroll
    for (int i = 0; i < 32; ++i)
      hacc = fmaf(__shfl(h1, hh2 * 32 + i), wc2reg[i], hacc);
    hacc += __shfl_xor(hacc, 1);
    const float h2 = fmaxf(hacc, 0.f);
    float p = h2 * cw * 0.5f;
#pragma unroll
    for (int o = 32; o; o >>= 1) p += __shfl_xor(p, o);
    if (l == 0) {
      const float z = p;
      const float l0 = z + cb0, l1 = z + cb1, l2 = z + cb2;
      const float s0 = sigmoidf_(l0), s1 = sigmoidf_(l1), s2 = sigmoidf_(l2);
      const float q0 = s0, q1 = s0 * s1, q2 = s0 * s1 * s2;
      const size_t bt = (size_t)rowbase + r;
      out_theta[bt] = theta;
      out_alpha[bt] = alpha;
      out_beta[bt * 3 + 0] = be0;
      out_beta[bt * 3 + 1] = be1;
      out_beta[bt * 3 + 2] = be2;
      out_logit[bt * 3 + 0] = l0;
      out_logit[bt * 3 + 1] = l1;
      out_logit[bt * 3 + 2] = l2;
      out_probs[bt * 4 + 0] = 1.f - q0;
      out_probs[bt * 4 + 1] = q0 - q1;
      out_probs[bt * 4 + 2] = q1 - q2;
      out_probs[bt * 4 + 3] = q2;
    }
  }
}

extern "C" void kernel_launch(void* const* d_in, const int* in_sizes, int n_in,
                              void* d_out, int out_size, void* d_ws, size_t ws_size,
                              hipStream_t stream) {
  const int*   q_data    = (const int*)d_in[0];
  const int*   r_data    = (const int*)d_in[1];
  const float* q_embed   = (const float*)d_in[2];
  const float* key_mem   = (const float*)d_in[3];
  const float* init_mv   = (const float*)d_in[4];
  const float* W_value   = (const float*)d_in[5];
  const float* b_value   = (const float*)d_in[6];
  const float* W_erase   = (const float*)d_in[7];
  const float* b_erase   = (const float*)d_in[8];
  const float* W_add     = (const float*)d_in[9];
  const float* b_add     = (const float*)d_in[10];
  const float* W_summary = (const float*)d_in[11];
  const float* b_summary = (const float*)d_in[12];
  const float* W_theta   = (const float*)d_in[13];
  const float* b_theta   = (const float*)d_in[14];
  const float* W_beta    = (const float*)d_in[15];
  const float* b_beta    = (const float*)d_in[16];
  const float* W_disc    = (const float*)d_in[17];
  const float* b_disc    = (const float*)d_in[18];
  const float* W_c1      = (const float*)d_in[19];
  const float* b_c1      = (const float*)d_in[20];
  const float* W_c2      = (const float*)d_in[21];
  const float* b_c2      = (const float*)d_in[22];
  const float* coral_w   = (const float*)d_in[23];
  const float* coral_b   = (const float*)d_in[24];

  float* ws = (float*)d_ws;
  size_t off = 0;
  float2* EA      = (float2*)(ws + off); off += (size_t)RROWS * VDIM * 2;
  float* w_tab    = ws + off; off += (size_t)QD * MM;
  float* Sq_tab   = ws + off; off += (size_t)QD * FDIM;
  float* aq_tab   = ws + off; off += 5120;
  float* beta_tab = ws + off; off += 15104;
  _Float16* Wh = (_Float16*)(ws + off); off += (VDIM * FDIM) / 2;
  _Float16* Rd = (_Float16*)(ws + off);

  k_prep<<<dim3(128), dim3(256), 0, stream>>>(W_summary, Wh);

  k_ea<<<dim3((RROWS + 31) / 32), dim3(256), 0, stream>>>(
      W_value, b_value, W_erase, b_erase, W_add, b_add, EA);

  k_q<<<dim3(QD), dim3(256), 0, stream>>>(
      q_embed, key_mem, W_summary, b_summary, W_disc, W_beta, b_beta,
      w_tab, Sq_tab, aq_tab, beta_tab);

  k_rec4<<<dim3(BB * 4), dim3(512), 0, stream>>>(
      q_data, r_data, init_mv, EA, w_tab, Rd);

  k_head<<<dim3((BB * SS) / 64), dim3(256), 0, stream>>>(
      q_data, Rd, Wh, Sq_tab, aq_tab, beta_tab,
      W_theta, b_theta, W_disc, b_disc,
      W_c1, b_c1, W_c2, b_c2, coral_w, coral_b, (float*)d_out);
}

// Round 7
// 979.459 us; speedup vs baseline: 1.1642x; 1.0101x over previous
//
#include <hip/hip_runtime.h>
#include <math.h>

#define BB 128
#define SS 1024
#define MM 64
#define KDIM 128
#define VDIM 256
#define FDIM 128
#define QNUM 5000
#define QD 5001            // q ids 0..5000
#define RROWS (4 * QD)     // 20004 distinct (r,q) rows

#define L0 100             // wave-0 chunk (replay-only)
#define LC 132             // waves 1..7 chunk (accum A+B then replay)
#define MA 40              // m-split: pass A covers m [0,40)
#define MB 24              // pass B covers m [40,64)

typedef _Float16 half2_t __attribute__((ext_vector_type(2)));
typedef float f2 __attribute__((ext_vector_type(2)));
union U4 { uint4 u; half2_t h[4]; };

#if defined(__has_builtin)
#if __has_builtin(__builtin_amdgcn_fdot2)
#define HAVE_FDOT2 1
#endif
#if __has_builtin(__builtin_elementwise_fma)
#define HAVE_EFMA 1
#endif
#endif

__device__ __forceinline__ float dot2_(half2_t a, half2_t b, float c) {
#ifdef HAVE_FDOT2
  return __builtin_amdgcn_fdot2(a, b, c, false);
#else
  return c + (float)a[0] * (float)b[0] + (float)a[1] * (float)b[1];
#endif
}

// packed f32 fma -> v_pk_fma_f32 (full-rate dual fp32 on CDNA)
__device__ __forceinline__ f2 pkfma(f2 a, f2 b, f2 c) {
#ifdef HAVE_EFMA
  return __builtin_elementwise_fma(a, b, c);
#else
  f2 r; r.x = fmaf(a.x, b.x, c.x); r.y = fmaf(a.y, b.y, c.y); return r;
#endif
}

__device__ __forceinline__ float sigmoidf_(float x) { return 1.0f / (1.0f + expf(-x)); }
__device__ __forceinline__ float softplusf_(float x) { return (x > 20.0f) ? x : log1pf(expf(x)); }

// ---------------- K0: W_summary read-part -> f16, [f][k] layout ----------------
__global__ __launch_bounds__(256) void k_prep(const float* __restrict__ W_summary,
                                              _Float16* __restrict__ Wh)
{
  const int e = blockIdx.x * 256 + threadIdx.x;   // 0..32767
  const int f = e >> 8, k = e & 255;
  Wh[(size_t)f * 256 + k] = (_Float16)W_summary[(size_t)k * FDIM + f];
}

// ---------------- K1: E/A table over all (r,q): packed (e,a) f2 accumulators ----------------
__global__ __launch_bounds__(256) void k_ea(
    const float* __restrict__ Wv, const float* __restrict__ bv,
    const float* __restrict__ We, const float* __restrict__ be,
    const float* __restrict__ Wa, const float* __restrict__ ba,
    float2* __restrict__ EA)
{
  const int tid = threadIdx.x;
  const int base = blockIdx.x * 32;
  __shared__ float sve[32][256];
#pragma unroll
  for (int j = 0; j < 32; ++j) {
    const int rr = base + j;
    float v = bv[tid];
    if (rr < RROWS) {
      const int q = rr % QD;
      const int r = rr / QD;
      if (q >= 1) {
        const float sc = (float)r * (1.0f / 3.0f);
        v += Wv[(size_t)(q - 1) * VDIM + tid] + sc * Wv[(size_t)(QNUM + q - 1) * VDIM + tid];
      }
    }
    sve[j][tid] = v;
  }
  __syncthreads();
  f2 acc[32];
#pragma unroll
  for (int j = 0; j < 32; ++j) acc[j] = (f2){0.f, 0.f};
#pragma unroll 4
  for (int i = 0; i < 256; ++i) {
    f2 w; w.x = We[i * VDIM + tid]; w.y = Wa[i * VDIM + tid];
#pragma unroll
    for (int j = 0; j < 32; ++j) {
      const float s = sve[j][i];
      acc[j] = pkfma((f2){s, s}, w, acc[j]);
    }
  }
  const float bev = be[tid], bav = ba[tid];
#pragma unroll
  for (int j = 0; j < 32; ++j) {
    const int rr = base + j;
    if (rr < RROWS) {
      float2 p;
      p.x = sigmoidf_(acc[j].x + bev);
      p.y = tanhf(acc[j].y + bav);
      EA[(size_t)rr * VDIM + tid] = p;
    }
  }
}

// ---------------- K2: per-q tables: w (softmax), Sq, aq, betas ----------------
__global__ __launch_bounds__(256) void k_q(
    const float* __restrict__ q_embed, const float* __restrict__ key_mem,
    const float* __restrict__ W_summary, const float* __restrict__ b_summary,
    const float* __restrict__ W_disc,
    const float* __restrict__ W_beta, const float* __restrict__ b_beta,
    float* __restrict__ w_tab, float* __restrict__ Sq_tab,
    float* __restrict__ aq_tab, float* __restrict__ beta_tab)
{
  const int q = blockIdx.x;
  const int tid = threadIdx.x;
  const int wave = tid >> 6, l = tid & 63;
  __shared__ float qe[KDIM];
  __shared__ float slog[MM];
  if (tid < KDIM) qe[tid] = q_embed[(size_t)q * KDIM + tid];
  __syncthreads();
  {
    const int m = tid >> 2, j = tid & 3;
    const float* krow = key_mem + m * KDIM + j * 32;
    const float* qrow = qe + j * 32;
    float acc = 0.f;
#pragma unroll
    for (int k = 0; k < 32; ++k) {
      const int i = (k + tid) & 31;
      acc = fmaf(qrow[i], krow[i], acc);
    }
    acc += __shfl_xor(acc, 1);
    acc += __shfl_xor(acc, 2);
    if (j == 0) slog[m] = acc;
  }
  __syncthreads();
  if (wave == 0) {
    const float x = slog[l];
    float mx = x;
#pragma unroll
    for (int o = 32; o; o >>= 1) mx = fmaxf(mx, __shfl_xor(mx, o));
    const float e = expf(x - mx);
    float s = e;
#pragma unroll
    for (int o = 32; o; o >>= 1) s += __shfl_xor(s, o);
    w_tab[(size_t)q * MM + l] = e / s;
  } else if (wave == 1) {
    float p = qe[l] * W_disc[KDIM + l] + qe[64 + l] * W_disc[KDIM + 64 + l];
#pragma unroll
    for (int o = 32; o; o >>= 1) p += __shfl_xor(p, o);
    if (l == 0) aq_tab[q] = p;
  } else if (wave == 2) {
    float p0 = qe[l] * W_beta[l * 3 + 0] + qe[64 + l] * W_beta[(64 + l) * 3 + 0];
    float p1 = qe[l] * W_beta[l * 3 + 1] + qe[64 + l] * W_beta[(64 + l) * 3 + 1];
    float p2 = qe[l] * W_beta[l * 3 + 2] + qe[64 + l] * W_beta[(64 + l) * 3 + 2];
#pragma unroll
    for (int o = 32; o; o >>= 1) {
      p0 += __shfl_xor(p0, o); p1 += __shfl_xor(p1, o); p2 += __shfl_xor(p2, o);
    }
    if (l == 0) {
      beta_tab[(size_t)q * 3 + 0] = p0 + b_beta[0];
      beta_tab[(size_t)q * 3 + 1] = p1 + b_beta[1];
      beta_tab[(size_t)q * 3 + 2] = p2 + b_beta[2];
    }
  }
  {
    const int f = tid >> 1, h = tid & 1;
    float acc = 0.f;
#pragma unroll 8
    for (int ii = 0; ii < 64; ++ii)
      acc = fmaf(qe[h * 64 + ii], W_summary[(size_t)(VDIM + h * 64 + ii) * FDIM + f], acc);
    acc += __shfl_xor(acc, 1);
    if (h == 0) Sq_tab[(size_t)q * FDIM + f] = acc + b_summary[f];
  }
}

// ---------------- K3: chunked scan, packed f32 math, 40/24 m-split ----------------
__global__ __launch_bounds__(512, 2) void k_rec5(
    const int* __restrict__ q_data, const int* __restrict__ r_data,
    const float* __restrict__ init_mv,
    const float2* __restrict__ EA, const float* __restrict__ w_tab,
    _Float16* __restrict__ Rd)
{
  const int tid = threadIdx.x;
  const int wave = tid >> 6, lane = tid & 63;
  const int b = blockIdx.x >> 2, vc = blockIdx.x & 3;
  const int v = vc * 64 + lane;

  __shared__ int s_q[SS];
  __shared__ int s_r[SS];
  __shared__ __align__(16) float s_w[8][8][MM];   // per-wave ring (wave-synchronous)
  __shared__ float s_R[MM * 64];                  // running boundary state [m][lane]

  for (int i = tid; i < SS; i += 512) {
    s_q[i] = q_data[b * SS + i];
    s_r[i] = r_data[b * SS + i];
  }
  __syncthreads();

  const int tb = (wave == 0) ? 0 : (L0 + (wave - 1) * LC);

  f2 mv2[MM / 2];
  f2 D2[MA / 2], U2[MA / 2];

  // ---- replay: evolve mv (all 64 m), store reads ----
  auto replay = [&](int base, int n) {
    float eD[4], aD[4];
#pragma unroll
    for (int j = 0; j < 4; ++j) {
      const int t = base + j;
      const int q = s_q[t];
      const float2 ea = EA[((size_t)(s_r[t] * QD + q)) * VDIM + v];
      eD[j] = ea.x; aD[j] = ea.y;
      s_w[wave][j][lane] = w_tab[(size_t)q * MM + lane];
    }
    const int ng = n >> 2;
    for (int g = 0; g < ng; ++g) {
      const int cb = (g & 1) << 2, nb = ((g + 1) & 1) << 2;
      float eN[4], aN[4];
#pragma unroll
      for (int j = 0; j < 4; ++j) {
        int tp = base + g * 4 + 4 + j; if (tp >= base + n) tp = base + n - 1;
        const int q = s_q[tp];
        const float2 ea = EA[((size_t)(s_r[tp] * QD + q)) * VDIM + v];
        eN[j] = ea.x; aN[j] = ea.y;
        s_w[wave][nb + j][lane] = w_tab[(size_t)q * MM + lane];
      }
#pragma unroll
      for (int j = 0; j < 4; ++j) {
        const float4* w4 = (const float4*)s_w[wave][cb + j];
        const f2 e2 = {eD[j], eD[j]}, a2 = {aD[j], aD[j]};
        f2 rdA = {0.f, 0.f}, rdB = {0.f, 0.f};
#pragma unroll
        for (int k = 0; k < 16; ++k) {
          const float4 ww = w4[k];
          const f2 w0 = {ww.x, ww.y}, w1 = {ww.z, ww.w};
          rdA = pkfma(w0, mv2[2 * k], rdA);
          f2 t0 = pkfma(-e2, mv2[2 * k], a2);
          mv2[2 * k] = pkfma(w0, t0, mv2[2 * k]);
          rdB = pkfma(w1, mv2[2 * k + 1], rdB);
          f2 t1 = pkfma(-e2, mv2[2 * k + 1], a2);
          mv2[2 * k + 1] = pkfma(w1, t1, mv2[2 * k + 1]);
        }
        const f2 rs = rdA + rdB;
        Rd[((size_t)b * SS + base + g * 4 + j) * VDIM + v] = (_Float16)(rs.x + rs.y);
      }
#pragma unroll
      for (int j = 0; j < 4; ++j) { eD[j] = eN[j]; aD[j] = aN[j]; }
    }
  };

  // ---- accum pass A: (D,U) for m in [0,MA) ----
  auto accumA = [&](int base, int n) {
#pragma unroll
    for (int k = 0; k < MA / 2; ++k) { D2[k] = (f2){1.f, 1.f}; U2[k] = (f2){0.f, 0.f}; }
    float eD[4], aD[4];
#pragma unroll
    for (int j = 0; j < 4; ++j) {
      const int t = base + j;
      const int q = s_q[t];
      const float2 ea = EA[((size_t)(s_r[t] * QD + q)) * VDIM + v];
      eD[j] = ea.x; aD[j] = ea.y;
      s_w[wave][j][lane] = w_tab[(size_t)q * MM + lane];
    }
    const int ng = n >> 2;
    for (int g = 0; g < ng; ++g) {
      const int cb = (g & 1) << 2, nb = ((g + 1) & 1) << 2;
      float eN[4], aN[4];
#pragma unroll
      for (int j = 0; j < 4; ++j) {
        int tp = base + g * 4 + 4 + j; if (tp >= base + n) tp = base + n - 1;
        const int q = s_q[tp];
        const float2 ea = EA[((size_t)(s_r[tp] * QD + q)) * VDIM + v];
        eN[j] = ea.x; aN[j] = ea.y;
        s_w[wave][nb + j][lane] = w_tab[(size_t)q * MM + lane];
      }
#pragma unroll
      for (int j = 0; j < 4; ++j) {
        const float4* w4 = (const float4*)s_w[wave][cb + j];
        const f2 e2 = {eD[j], eD[j]}, a2 = {aD[j], aD[j]};
#pragma unroll
        for (int k = 0; k < MA / 4; ++k) {
          const float4 ww = w4[k];
          const f2 w0 = {ww.x, ww.y}, w1 = {ww.z, ww.w};
          const f2 c0 = w0 * e2, c1 = w1 * e2;
          D2[2 * k]     = pkfma(-c0, D2[2 * k], D2[2 * k]);
          U2[2 * k]     = pkfma(-c0, U2[2 * k], U2[2 * k]);
          U2[2 * k]     = pkfma(w0, a2, U2[2 * k]);
          D2[2 * k + 1] = pkfma(-c1, D2[2 * k + 1], D2[2 * k + 1]);
          U2[2 * k + 1] = pkfma(-c1, U2[2 * k + 1], U2[2 * k + 1]);
          U2[2 * k + 1] = pkfma(w1, a2, U2[2 * k + 1]);
        }
      }
#pragma unroll
      for (int j = 0; j < 4; ++j) { eD[j] = eN[j]; aD[j] = aN[j]; }
    }
  };

  // ---- accum pass B: (D,U) for m in [MA,64) — MB/2 f2 regs live, mv[0:MA] held ----
  auto accumB = [&](int base, int n) {
#pragma unroll
    for (int k = 0; k < MB / 2; ++k) { D2[k] = (f2){1.f, 1.f}; U2[k] = (f2){0.f, 0.f}; }
    float eD[4], aD[4];
#pragma unroll
    for (int j = 0; j < 4; ++j) {
      const int t = base + j;
      const int q = s_q[t];
      const float2 ea = EA[((size_t)(s_r[t] * QD + q)) * VDIM + v];
      eD[j] = ea.x; aD[j] = ea.y;
      s_w[wave][j][lane] = w_tab[(size_t)q * MM + lane];
    }
    const int ng = n >> 2;
    for (int g = 0; g < ng; ++g) {
      const int cb = (g & 1) << 2, nb = ((g + 1) & 1) << 2;
      float eN[4], aN[4];
#pragma unroll
      for (int j = 0; j < 4; ++j) {
        int tp = base + g * 4 + 4 + j; if (tp >= base + n) tp = base + n - 1;
        const int q = s_q[tp];
        const float2 ea = EA[((size_t)(s_r[tp] * QD + q)) * VDIM + v];
        eN[j] = ea.x; aN[j] = ea.y;
        s_w[wave][nb + j][lane] = w_tab[(size_t)q * MM + lane];
      }
#pragma unroll
      for (int j = 0; j < 4; ++j) {
        const float4* w4 = (const float4*)(s_w[wave][cb + j] + MA);
        const f2 e2 = {eD[j], eD[j]}, a2 = {aD[j], aD[j]};
#pragma unroll
        for (int k = 0; k < MB / 4; ++k) {
          const float4 ww = w4[k];
          const f2 w0 = {ww.x, ww.y}, w1 = {ww.z, ww.w};
          const f2 c0 = w0 * e2, c1 = w1 * e2;
          D2[2 * k]     = pkfma(-c0, D2[2 * k], D2[2 * k]);
          U2[2 * k]     = pkfma(-c0, U2[2 * k], U2[2 * k]);
          U2[2 * k]     = pkfma(w0, a2, U2[2 * k]);
          D2[2 * k + 1] = pkfma(-c1, D2[2 * k + 1], D2[2 * k + 1]);
          U2[2 * k + 1] = pkfma(-c1, U2[2 * k + 1], U2[2 * k + 1]);
          U2[2 * k + 1] = pkfma(w1, a2, U2[2 * k + 1]);
        }
      }
#pragma unroll
      for (int j = 0; j < 4; ++j) { eD[j] = eN[j]; aD[j] = aN[j]; }
    }
  };

  // ---- phase 1: wave0 replay + publish boundary; waves>0 accum pass A ----
  if (wave == 0) {
#pragma unroll
    for (int k = 0; k < MM / 2; ++k) {
      mv2[k].x = init_mv[(2 * k) * VDIM + v];
      mv2[k].y = init_mv[(2 * k + 1) * VDIM + v];
    }
    replay(0, L0);
#pragma unroll
    for (int k = 0; k < MM / 2; ++k) {
      s_R[(2 * k) * 64 + lane] = mv2[k].x;
      s_R[(2 * k + 1) * 64 + lane] = mv2[k].y;
    }
  } else {
    accumA(tb, LC);
  }
  __syncthreads();

  // ---- scan A: propagate boundaries for m in [0,MA) ----
  for (int rr = 1; rr < 8; ++rr) {
    if (wave == rr) {
#pragma unroll
      for (int k = 0; k < MA / 2; ++k) {
        const float x0 = s_R[(2 * k) * 64 + lane];
        const float x1 = s_R[(2 * k + 1) * 64 + lane];
        s_R[(2 * k) * 64 + lane]     = fmaf(x0, D2[k].x, U2[k].x);
        s_R[(2 * k + 1) * 64 + lane] = fmaf(x1, D2[k].y, U2[k].y);
        mv2[k].x = x0; mv2[k].y = x1;
      }
    }
    __syncthreads();
  }

  // ---- phase 1B: accum pass B ----
  if (wave > 0) accumB(tb, LC);
  __syncthreads();

  // ---- scan B: propagate boundaries for m in [MA,64) ----
  for (int rr = 1; rr < 8; ++rr) {
    if (wave == rr) {
#pragma unroll
      for (int k = 0; k < MB / 2; ++k) {
        const float x0 = s_R[(MA + 2 * k) * 64 + lane];
        const float x1 = s_R[(MA + 2 * k + 1) * 64 + lane];
        s_R[(MA + 2 * k) * 64 + lane]     = fmaf(x0, D2[k].x, U2[k].x);
        s_R[(MA + 2 * k + 1) * 64 + lane] = fmaf(x1, D2[k].y, U2[k].y);
        mv2[MA / 2 + k].x = x0; mv2[MA / 2 + k].y = x1;
      }
    }
    __syncthreads();
  }

  // ---- phase 3: replay chunks 1..7 from boundary states ----
  if (wave > 0) replay(tb, LC);
}

// ---------------- K4: parallel summary GEMM + heads + CORAL over all (b,t) ----------------
__global__ __launch_bounds__(256) void k_head(
    const int* __restrict__ q_data,
    const _Float16* __restrict__ Rd, const _Float16* __restrict__ Wh,
    const float* __restrict__ Sq_tab, const float* __restrict__ aq_tab,
    const float* __restrict__ beta_tab,
    const float* __restrict__ W_theta, const float* __restrict__ b_theta,
    const float* __restrict__ W_disc, const float* __restrict__ b_disc,
    const float* __restrict__ W_c1, const float* __restrict__ b_c1,
    const float* __restrict__ W_c2, const float* __restrict__ b_c2,
    const float* __restrict__ coral_w, const float* __restrict__ coral_b,
    float* __restrict__ out)
{
  const int tid = threadIdx.x;
  const int w = tid >> 6, l = tid & 63;
  const int rowbase = blockIdx.x * 64;           // 64 rows (same b: 64 | 1024)
  const int b = rowbase >> 10;
  const int t0 = rowbase & (SS - 1);

  __shared__ __align__(16) _Float16 s_A[64 * 256];   // 32 KB
  __shared__ __align__(16) _Float16 s_sum[64 * 128]; // 16 KB
  __shared__ int   s_q[64];
  __shared__ float s_aq[64];
  __shared__ float s_be[64][3];

  {
    const uint4* src = (const uint4*)(Rd + (size_t)rowbase * VDIM);
    uint4* dst = (uint4*)s_A;
    for (int i = tid; i < (64 * 256 * 2) / 16; i += 256) dst[i] = src[i];
  }
  if (tid < 64) {
    const int q = q_data[b * SS + t0 + tid];
    s_q[tid] = q;
    s_aq[tid] = aq_tab[q];
    s_be[tid][0] = beta_tab[(size_t)q * 3 + 0];
    s_be[tid][1] = beta_tab[(size_t)q * 3 + 1];
    s_be[tid][2] = beta_tab[(size_t)q * 3 + 2];
  }

  const int fp = l >> 1, g = l & 1;
  const int fbase = (w & 1) * 64;
  const int f0 = fbase + 2 * fp, f1 = f0 + 1;
  U4 wr0[16], wr1[16];
  {
    const uint4* p0 = (const uint4*)(Wh + (size_t)f0 * 256 + g * 128);
    const uint4* p1 = (const uint4*)(Wh + (size_t)f1 * 256 + g * 128);
#pragma unroll
    for (int i = 0; i < 16; ++i) { wr0[i].u = p0[i]; wr1[i].u = p1[i]; }
  }
  __syncthreads();

  for (int rp = 0; rp < 32; ++rp) {
    const int r = 2 * rp + (w >> 1);
    const uint4* a4 = (const uint4*)(s_A + r * 256 + g * 128);
    float a0 = 0.f, a1 = 0.f, c0 = 0.f, c1 = 0.f;
#pragma unroll
    for (int i = 0; i < 16; i += 2) {
      U4 x; x.u = a4[i];
      U4 y; y.u = a4[i + 1];
#pragma unroll
      for (int j = 0; j < 4; ++j) {
        a0 = dot2_(x.h[j], wr0[i].h[j], a0);
        a1 = dot2_(x.h[j], wr1[i].h[j], a1);
        c0 = dot2_(y.h[j], wr0[i + 1].h[j], c0);
        c1 = dot2_(y.h[j], wr1[i + 1].h[j], c1);
      }
    }
    float f0acc = a0 + c0, f1acc = a1 + c1;
    f0acc += __shfl_xor(f0acc, 1);
    f1acc += __shfl_xor(f1acc, 1);
    if (g == 0) {
      const float2 sq = *(const float2*)(Sq_tab + (size_t)s_q[r] * FDIM + f0);
      s_sum[r * 128 + f0] = (_Float16)tanhf(f0acc + sq.x);
      s_sum[r * 128 + f1] = (_Float16)tanhf(f1acc + sq.y);
    }
  }
  __syncthreads();

  const float tw0 = W_theta[l], tw1 = W_theta[64 + l], tb = b_theta[0];
  const float dw0 = W_disc[l], dw1 = W_disc[64 + l], db = b_disc[0];
  float wc1reg[5];
#pragma unroll
  for (int i = 0; i < 5; ++i) wc1reg[i] = W_c1[i * 64 + l];
  const float bc1 = b_c1[l];
  const int jj = l >> 1, hh2 = l & 1;
  float wc2reg[32];
#pragma unroll
  for (int i = 0; i < 32; ++i) wc2reg[i] = W_c2[(hh2 * 32 + i) * 32 + jj];
  const float bc2 = b_c2[jj];
  const float cw = coral_w[jj];
  const float cb0 = coral_b[0], cb1 = coral_b[1], cb2 = coral_b[2];

  float* out_theta = out;
  float* out_beta  = out + (size_t)BB * SS;
  float* out_alpha = out + (size_t)BB * SS * 4;
  float* out_probs = out + (size_t)BB * SS * 5;
  float* out_logit = out + (size_t)BB * SS * 9;

  for (int rr = 0; rr < 16; ++rr) {
    const int r = w * 16 + rr;
    const float su0 = (float)s_sum[r * 128 + l];
    const float su1 = (float)s_sum[r * 128 + 64 + l];
    float at = su0 * tw0 + su1 * tw1;
    float ad = su0 * dw0 + su1 * dw1;
#pragma unroll
    for (int o = 32; o; o >>= 1) { at += __shfl_xor(at, o); ad += __shfl_xor(ad, o); }
    const float theta = (at + tb) * 3.0f;
    const float alpha = softplusf_(ad + s_aq[r] + db);
    const float be0 = s_be[r][0], be1 = s_be[r][1], be2 = s_be[r][2];
    float h1 = bc1;
    h1 = fmaf(theta, wc1reg[0], h1);
    h1 = fmaf(alpha, wc1reg[1], h1);
    h1 = fmaf(be0, wc1reg[2], h1);
    h1 = fmaf(be1, wc1reg[3], h1);
    h1 = fmaf(be2, wc1reg[4], h1);
    h1 = fmaxf(h1, 0.f);
    float hacc = hh2 ? 0.f : bc2;
#pragma unroll
    for (int i = 0; i < 32; ++i)
      hacc = fmaf(__shfl(h1, hh2 * 32 + i), wc2reg[i], hacc);
    hacc += __shfl_xor(hacc, 1);
    const float h2 = fmaxf(hacc, 0.f);
    float p = h2 * cw * 0.5f;
#pragma unroll
    for (int o = 32; o; o >>= 1) p += __shfl_xor(p, o);
    if (l == 0) {
      const float z = p;
      const float l0 = z + cb0, l1 = z + cb1, l2 = z + cb2;
      const float s0 = sigmoidf_(l0), s1 = sigmoidf_(l1), s2 = sigmoidf_(l2);
      const float q0 = s0, q1 = s0 * s1, q2 = s0 * s1 * s2;
      const size_t bt = (size_t)rowbase + r;
      out_theta[bt] = theta;
      out_alpha[bt] = alpha;
      out_beta[bt * 3 + 0] = be0;
      out_beta[bt * 3 + 1] = be1;
      out_beta[bt * 3 + 2] = be2;
      out_logit[bt * 3 + 0] = l0;
      out_logit[bt * 3 + 1] = l1;
      out_logit[bt * 3 + 2] = l2;
      out_probs[bt * 4 + 0] = 1.f - q0;
      out_probs[bt * 4 + 1] = q0 - q1;
      out_probs[bt * 4 + 2] = q1 - q2;
      out_probs[bt * 4 + 3] = q2;
    }
  }
}

extern "C" void kernel_launch(void* const* d_in, const int* in_sizes, int n_in,
                              void* d_out, int out_size, void* d_ws, size_t ws_size,
                              hipStream_t stream) {
  const int*   q_data    = (const int*)d_in[0];
  const int*   r_data    = (const int*)d_in[1];
  const float* q_embed   = (const float*)d_in[2];
  const float* key_mem   = (const float*)d_in[3];
  const float* init_mv   = (const float*)d_in[4];
  const float* W_value   = (const float*)d_in[5];
  const float* b_value   = (const float*)d_in[6];
  const float* W_erase   = (const float*)d_in[7];
  const float* b_erase   = (const float*)d_in[8];
  const float* W_add     = (const float*)d_in[9];
  const float* b_add     = (const float*)d_in[10];
  const float* W_summary = (const float*)d_in[11];
  const float* b_summary = (const float*)d_in[12];
  const float* W_theta   = (const float*)d_in[13];
  const float* b_theta   = (const float*)d_in[14];
  const float* W_beta    = (const float*)d_in[15];
  const float* b_beta    = (const float*)d_in[16];
  const float* W_disc    = (const float*)d_in[17];
  const float* b_disc    = (const float*)d_in[18];
  const float* W_c1      = (const float*)d_in[19];
  const float* b_c1      = (const float*)d_in[20];
  const float* W_c2      = (const float*)d_in[21];
  const float* b_c2      = (const float*)d_in[22];
  const float* coral_w   = (const float*)d_in[23];
  const float* coral_b   = (const float*)d_in[24];

  float* ws = (float*)d_ws;
  size_t off = 0;
  float2* EA      = (float2*)(ws + off); off += (size_t)RROWS * VDIM * 2;
  float* w_tab    = ws + off; off += (size_t)QD * MM;
  float* Sq_tab   = ws + off; off += (size_t)QD * FDIM;
  float* aq_tab   = ws + off; off += 5120;
  float* beta_tab = ws + off; off += 15104;
  _Float16* Wh = (_Float16*)(ws + off); off += (VDIM * FDIM) / 2;
  _Float16* Rd = (_Float16*)(ws + off);

  k_prep<<<dim3(128), dim3(256), 0, stream>>>(W_summary, Wh);

  k_ea<<<dim3((RROWS + 31) / 32), dim3(256), 0, stream>>>(
      W_value, b_value, W_erase, b_erase, W_add, b_add, EA);

  k_q<<<dim3(QD), dim3(256), 0, stream>>>(
      q_embed, key_mem, W_summary, b_summary, W_disc, W_beta, b_beta,
      w_tab, Sq_tab, aq_tab, beta_tab);

  k_rec5<<<dim3(BB * 4), dim3(512), 0, stream>>>(
      q_data, r_data, init_mv, EA, w_tab, Rd);

  k_head<<<dim3((BB * SS) / 64), dim3(256), 0, stream>>>(
      q_data, Rd, Wh, Sq_tab, aq_tab, beta_tab,
      W_theta, b_theta, W_disc, b_disc,
      W_c1, b_c1, W_c2, b_c2, coral_w, coral_b, (float*)d_out);
}

// Round 8
// 865.062 us; speedup vs baseline: 1.3182x; 1.1322x over previous
//
#include <hip/hip_runtime.h>
#include <math.h>

#define BB 128
#define SS 1024
#define MM 64
#define KDIM 128
#define VDIM 256
#define FDIM 128
#define QNUM 5000
#define QD 5001            // q ids 0..5000
#define RROWS (4 * QD)     // 20004 distinct (r,q) rows

#define LCH 128            // all 8 chunks equal: 8*128 = 1024
#define MA 40              // m-split: pass A covers m [0,40)
#define MB 24              // pass B covers m [40,64)

typedef _Float16 half2_t __attribute__((ext_vector_type(2)));
typedef float f2 __attribute__((ext_vector_type(2)));
union U4 { uint4 u; half2_t h[4]; };

#if defined(__has_builtin)
#if __has_builtin(__builtin_amdgcn_fdot2)
#define HAVE_FDOT2 1
#endif
#if __has_builtin(__builtin_elementwise_fma)
#define HAVE_EFMA 1
#endif
#endif

__device__ __forceinline__ float dot2_(half2_t a, half2_t b, float c) {
#ifdef HAVE_FDOT2
  return __builtin_amdgcn_fdot2(a, b, c, false);
#else
  return c + (float)a[0] * (float)b[0] + (float)a[1] * (float)b[1];
#endif
}

__device__ __forceinline__ f2 pkfma(f2 a, f2 b, f2 c) {
#ifdef HAVE_EFMA
  return __builtin_elementwise_fma(a, b, c);
#else
  f2 r; r.x = fmaf(a.x, b.x, c.x); r.y = fmaf(a.y, b.y, c.y); return r;
#endif
}

__device__ __forceinline__ float sigmoidf_(float x) { return 1.0f / (1.0f + expf(-x)); }
__device__ __forceinline__ float softplusf_(float x) { return (x > 20.0f) ? x : log1pf(expf(x)); }

// ---------------- K0: W_summary read-part -> f16, [f][k] layout ----------------
__global__ __launch_bounds__(256) void k_prep(const float* __restrict__ W_summary,
                                              _Float16* __restrict__ Wh)
{
  const int e = blockIdx.x * 256 + threadIdx.x;   // 0..32767
  const int f = e >> 8, k = e & 255;
  Wh[(size_t)f * 256 + k] = (_Float16)W_summary[(size_t)k * FDIM + f];
}

// ---------------- K1: E/A table over all (r,q): packed (e,a) f2 accumulators ----------------
__global__ __launch_bounds__(256) void k_ea(
    const float* __restrict__ Wv, const float* __restrict__ bv,
    const float* __restrict__ We, const float* __restrict__ be,
    const float* __restrict__ Wa, const float* __restrict__ ba,
    float2* __restrict__ EA)
{
  const int tid = threadIdx.x;
  const int base = blockIdx.x * 32;
  __shared__ float sve[32][256];
#pragma unroll
  for (int j = 0; j < 32; ++j) {
    const int rr = base + j;
    float v = bv[tid];
    if (rr < RROWS) {
      const int q = rr % QD;
      const int r = rr / QD;
      if (q >= 1) {
        const float sc = (float)r * (1.0f / 3.0f);
        v += Wv[(size_t)(q - 1) * VDIM + tid] + sc * Wv[(size_t)(QNUM + q - 1) * VDIM + tid];
      }
    }
    sve[j][tid] = v;
  }
  __syncthreads();
  f2 acc[32];
#pragma unroll
  for (int j = 0; j < 32; ++j) acc[j] = (f2){0.f, 0.f};
#pragma unroll 4
  for (int i = 0; i < 256; ++i) {
    f2 w; w.x = We[i * VDIM + tid]; w.y = Wa[i * VDIM + tid];
#pragma unroll
    for (int j = 0; j < 32; ++j) {
      const float s = sve[j][i];
      acc[j] = pkfma((f2){s, s}, w, acc[j]);
    }
  }
  const float bev = be[tid], bav = ba[tid];
#pragma unroll
  for (int j = 0; j < 32; ++j) {
    const int rr = base + j;
    if (rr < RROWS) {
      float2 p;
      p.x = sigmoidf_(acc[j].x + bev);
      p.y = tanhf(acc[j].y + bav);
      EA[(size_t)rr * VDIM + tid] = p;
    }
  }
}

// ---------------- K2: per-q tables (key_mem staged in LDS; Sq coalesced) ----------------
__global__ __launch_bounds__(256) void k_q(
    const float* __restrict__ q_embed, const float* __restrict__ key_mem,
    const float* __restrict__ W_summary, const float* __restrict__ b_summary,
    const float* __restrict__ W_disc,
    const float* __restrict__ W_beta, const float* __restrict__ b_beta,
    float* __restrict__ w_tab, float* __restrict__ Sq_tab,
    float* __restrict__ aq_tab, float* __restrict__ beta_tab)
{
  const int q = blockIdx.x;
  const int tid = threadIdx.x;
  const int wave = tid >> 6, l = tid & 63;
  __shared__ float s_key[MM * KDIM];   // 32 KB, coalesced staging
  __shared__ float qe[KDIM];
  __shared__ float slog[MM];
  __shared__ float s_half[FDIM];
  for (int i = tid; i < MM * KDIM; i += 256) s_key[i] = key_mem[i];
  if (tid < KDIM) qe[tid] = q_embed[(size_t)q * KDIM + tid];
  __syncthreads();
  {
    const int m = tid >> 2, j = tid & 3;
    const float* krow = s_key + m * KDIM + j * 32;
    const float* qrow = qe + j * 32;
    float acc = 0.f;
#pragma unroll
    for (int k = 0; k < 32; ++k) {
      const int i = (k + tid) & 31;
      acc = fmaf(qrow[i], krow[i], acc);
    }
    acc += __shfl_xor(acc, 1);
    acc += __shfl_xor(acc, 2);
    if (j == 0) slog[m] = acc;
  }
  __syncthreads();
  if (wave == 0) {
    const float x = slog[l];
    float mx = x;
#pragma unroll
    for (int o = 32; o; o >>= 1) mx = fmaxf(mx, __shfl_xor(mx, o));
    const float e = expf(x - mx);
    float s = e;
#pragma unroll
    for (int o = 32; o; o >>= 1) s += __shfl_xor(s, o);
    w_tab[(size_t)q * MM + l] = e / s;
  } else if (wave == 1) {
    float p = qe[l] * W_disc[KDIM + l] + qe[64 + l] * W_disc[KDIM + 64 + l];
#pragma unroll
    for (int o = 32; o; o >>= 1) p += __shfl_xor(p, o);
    if (l == 0) aq_tab[q] = p;
  } else if (wave == 2) {
    float p0 = qe[l] * W_beta[l * 3 + 0] + qe[64 + l] * W_beta[(64 + l) * 3 + 0];
    float p1 = qe[l] * W_beta[l * 3 + 1] + qe[64 + l] * W_beta[(64 + l) * 3 + 1];
    float p2 = qe[l] * W_beta[l * 3 + 2] + qe[64 + l] * W_beta[(64 + l) * 3 + 2];
#pragma unroll
    for (int o = 32; o; o >>= 1) {
      p0 += __shfl_xor(p0, o); p1 += __shfl_xor(p1, o); p2 += __shfl_xor(p2, o);
    }
    if (l == 0) {
      beta_tab[(size_t)q * 3 + 0] = p0 + b_beta[0];
      beta_tab[(size_t)q * 3 + 1] = p1 + b_beta[1];
      beta_tab[(size_t)q * 3 + 2] = p2 + b_beta[2];
    }
  }
  // Sq: lane f = tid&127 contiguous -> coalesced W_summary reads; halves via LDS
  {
    const int f = tid & 127, h = tid >> 7;
    float acc = 0.f;
#pragma unroll 8
    for (int k = 0; k < 64; ++k)
      acc = fmaf(qe[h * 64 + k], W_summary[(size_t)(VDIM + h * 64 + k) * FDIM + f], acc);
    if (h == 1) s_half[f] = acc;
    __syncthreads();
    if (h == 0) Sq_tab[(size_t)q * FDIM + f] = acc + s_half[f] + b_summary[f];
  }
}

// ---------------- K3: chunked scan, load->compute->ds_write pipeline ----------------
__global__ __launch_bounds__(512, 2) void k_rec6(
    const int* __restrict__ q_data, const int* __restrict__ r_data,
    const float* __restrict__ init_mv,
    const float2* __restrict__ EA, const float* __restrict__ w_tab,
    _Float16* __restrict__ Rd)
{
  const int tid = threadIdx.x;
  const int wave = tid >> 6, lane = tid & 63;
  const int b = blockIdx.x >> 2, vc = blockIdx.x & 3;
  const int v = vc * 64 + lane;

  __shared__ int s_q[SS];
  __shared__ int s_r[SS];
  __shared__ __align__(16) float s_w[8][8][MM];   // per-wave ring (wave-synchronous)
  __shared__ float s_R[MM * 64];                  // running boundary state [m][lane]

  for (int i = tid; i < SS; i += 512) {
    s_q[i] = q_data[b * SS + i];
    s_r[i] = r_data[b * SS + i];
  }
  __syncthreads();

  const int tb = wave * LCH;

  f2 mv2[MM / 2];
  f2 D2[MA / 2], U2[MA / 2];

  // ---- replay: evolve mv (all 64 m), store reads.  Pipeline: load -> compute -> ds_write ----
  auto replay = [&](int base) {
    float eD[4], aD[4], wN[4];
#pragma unroll
    for (int j = 0; j < 4; ++j) {
      const int t = base + j;
      const float2 ea = EA[((size_t)(s_r[t] * QD + s_q[t])) * VDIM + v];
      eD[j] = ea.x; aD[j] = ea.y;
      s_w[wave][j][lane] = w_tab[(size_t)s_q[t] * MM + lane];
    }
    for (int g = 0; g < LCH / 4; ++g) {
      const int cb = (g & 1) << 2, nb = ((g + 1) & 1) << 2;
      float eN[4], aN[4];
#pragma unroll
      for (int j = 0; j < 4; ++j) {
        int tp = base + g * 4 + 4 + j; if (tp >= base + LCH) tp = base + g * 4 + j;
        const int q = s_q[tp];
        const float2 ea = EA[((size_t)(s_r[tp] * QD + q)) * VDIM + v];
        eN[j] = ea.x; aN[j] = ea.y;
        wN[j] = w_tab[(size_t)q * MM + lane];
      }
      // compute group g (overlaps with the loads above)
#pragma unroll
      for (int j = 0; j < 4; ++j) {
        const float4* w4 = (const float4*)s_w[wave][cb + j];
        const f2 e2 = {eD[j], eD[j]}, a2 = {aD[j], aD[j]};
        f2 rdA = {0.f, 0.f}, rdB = {0.f, 0.f};
#pragma unroll
        for (int k = 0; k < 16; ++k) {
          const float4 ww = w4[k];
          const f2 w0 = {ww.x, ww.y}, w1 = {ww.z, ww.w};
          rdA = pkfma(w0, mv2[2 * k], rdA);
          f2 t0 = pkfma(-e2, mv2[2 * k], a2);
          mv2[2 * k] = pkfma(w0, t0, mv2[2 * k]);
          rdB = pkfma(w1, mv2[2 * k + 1], rdB);
          f2 t1 = pkfma(-e2, mv2[2 * k + 1], a2);
          mv2[2 * k + 1] = pkfma(w1, t1, mv2[2 * k + 1]);
        }
        const f2 rs = rdA + rdB;
        Rd[((size_t)b * SS + base + g * 4 + j) * VDIM + v] = (_Float16)(rs.x + rs.y);
      }
      // stage next group's w into LDS (vmcnt wait lands AFTER compute)
#pragma unroll
      for (int j = 0; j < 4; ++j) s_w[wave][nb + j][lane] = wN[j];
#pragma unroll
      for (int j = 0; j < 4; ++j) { eD[j] = eN[j]; aD[j] = aN[j]; }
    }
  };

  // ---- accum pass A: (D,U) for m in [0,MA) ----
  auto accumA = [&](int base) {
#pragma unroll
    for (int k = 0; k < MA / 2; ++k) { D2[k] = (f2){1.f, 1.f}; U2[k] = (f2){0.f, 0.f}; }
    float eD[4], aD[4], wN[4];
#pragma unroll
    for (int j = 0; j < 4; ++j) {
      const int t = base + j;
      const float2 ea = EA[((size_t)(s_r[t] * QD + s_q[t])) * VDIM + v];
      eD[j] = ea.x; aD[j] = ea.y;
      s_w[wave][j][lane] = w_tab[(size_t)s_q[t] * MM + lane];
    }
    for (int g = 0; g < LCH / 4; ++g) {
      const int cb = (g & 1) << 2, nb = ((g + 1) & 1) << 2;
      float eN[4], aN[4];
#pragma unroll
      for (int j = 0; j < 4; ++j) {
        int tp = base + g * 4 + 4 + j; if (tp >= base + LCH) tp = base + g * 4 + j;
        const int q = s_q[tp];
        const float2 ea = EA[((size_t)(s_r[tp] * QD + q)) * VDIM + v];
        eN[j] = ea.x; aN[j] = ea.y;
        wN[j] = w_tab[(size_t)q * MM + lane];
      }
#pragma unroll
      for (int j = 0; j < 4; ++j) {
        const float4* w4 = (const float4*)s_w[wave][cb + j];
        const f2 e2 = {eD[j], eD[j]}, a2 = {aD[j], aD[j]};
#pragma unroll
        for (int k = 0; k < MA / 4; ++k) {
          const float4 ww = w4[k];
          const f2 w0 = {ww.x, ww.y}, w1 = {ww.z, ww.w};
          const f2 c0 = w0 * e2, c1 = w1 * e2;
          D2[2 * k]     = pkfma(-c0, D2[2 * k], D2[2 * k]);
          U2[2 * k]     = pkfma(-c0, U2[2 * k], U2[2 * k]);
          U2[2 * k]     = pkfma(w0, a2, U2[2 * k]);
          D2[2 * k + 1] = pkfma(-c1, D2[2 * k + 1], D2[2 * k + 1]);
          U2[2 * k + 1] = pkfma(-c1, U2[2 * k + 1], U2[2 * k + 1]);
          U2[2 * k + 1] = pkfma(w1, a2, U2[2 * k + 1]);
        }
      }
#pragma unroll
      for (int j = 0; j < 4; ++j) s_w[wave][nb + j][lane] = wN[j];
#pragma unroll
      for (int j = 0; j < 4; ++j) { eD[j] = eN[j]; aD[j] = aN[j]; }
    }
  };

  // ---- accum pass B: (D,U) for m in [MA,64) ----
  auto accumB = [&](int base) {
#pragma unroll
    for (int k = 0; k < MB / 2; ++k) { D2[k] = (f2){1.f, 1.f}; U2[k] = (f2){0.f, 0.f}; }
    float eD[4], aD[4], wN[4];
#pragma unroll
    for (int j = 0; j < 4; ++j) {
      const int t = base + j;
      const float2 ea = EA[((size_t)(s_r[t] * QD + s_q[t])) * VDIM + v];
      eD[j] = ea.x; aD[j] = ea.y;
      s_w[wave][j][lane] = w_tab[(size_t)s_q[t] * MM + lane];
    }
    for (int g = 0; g < LCH / 4; ++g) {
      const int cb = (g & 1) << 2, nb = ((g + 1) & 1) << 2;
      float eN[4], aN[4];
#pragma unroll
      for (int j = 0; j < 4; ++j) {
        int tp = base + g * 4 + 4 + j; if (tp >= base + LCH) tp = base + g * 4 + j;
        const int q = s_q[tp];
        const float2 ea = EA[((size_t)(s_r[tp] * QD + q)) * VDIM + v];
        eN[j] = ea.x; aN[j] = ea.y;
        wN[j] = w_tab[(size_t)q * MM + lane];
      }
#pragma unroll
      for (int j = 0; j < 4; ++j) {
        const float4* w4 = (const float4*)(s_w[wave][cb + j] + MA);
        const f2 e2 = {eD[j], eD[j]}, a2 = {aD[j], aD[j]};
#pragma unroll
        for (int k = 0; k < MB / 4; ++k) {
          const float4 ww = w4[k];
          const f2 w0 = {ww.x, ww.y}, w1 = {ww.z, ww.w};
          const f2 c0 = w0 * e2, c1 = w1 * e2;
          D2[2 * k]     = pkfma(-c0, D2[2 * k], D2[2 * k]);
          U2[2 * k]     = pkfma(-c0, U2[2 * k], U2[2 * k]);
          U2[2 * k]     = pkfma(w0, a2, U2[2 * k]);
          D2[2 * k + 1] = pkfma(-c1, D2[2 * k + 1], D2[2 * k + 1]);
          U2[2 * k + 1] = pkfma(-c1, U2[2 * k + 1], U2[2 * k + 1]);
          U2[2 * k + 1] = pkfma(w1, a2, U2[2 * k + 1]);
        }
      }
#pragma unroll
      for (int j = 0; j < 4; ++j) s_w[wave][nb + j][lane] = wN[j];
#pragma unroll
      for (int j = 0; j < 4; ++j) { eD[j] = eN[j]; aD[j] = aN[j]; }
    }
  };

  // ---- phase 1: wave0 replay + publish boundary; waves>0 accum pass A ----
  if (wave == 0) {
#pragma unroll
    for (int k = 0; k < MM / 2; ++k) {
      mv2[k].x = init_mv[(2 * k) * VDIM + v];
      mv2[k].y = init_mv[(2 * k + 1) * VDIM + v];
    }
    replay(0);
#pragma unroll
    for (int k = 0; k < MM / 2; ++k) {
      s_R[(2 * k) * 64 + lane] = mv2[k].x;
      s_R[(2 * k + 1) * 64 + lane] = mv2[k].y;
    }
  } else {
    accumA(tb);
  }
  __syncthreads();

  // ---- scan A ----
  for (int rr = 1; rr < 8; ++rr) {
    if (wave == rr) {
#pragma unroll
      for (int k = 0; k < MA / 2; ++k) {
        const float x0 = s_R[(2 * k) * 64 + lane];
        const float x1 = s_R[(2 * k + 1) * 64 + lane];
        s_R[(2 * k) * 64 + lane]     = fmaf(x0, D2[k].x, U2[k].x);
        s_R[(2 * k + 1) * 64 + lane] = fmaf(x1, D2[k].y, U2[k].y);
        mv2[k].x = x0; mv2[k].y = x1;
      }
    }
    __syncthreads();
  }

  // ---- phase 1B: accum pass B ----
  if (wave > 0) accumB(tb);
  __syncthreads();

  // ---- scan B ----
  for (int rr = 1; rr < 8; ++rr) {
    if (wave == rr) {
#pragma unroll
      for (int k = 0; k < MB / 2; ++k) {
        const float x0 = s_R[(MA + 2 * k) * 64 + lane];
        const float x1 = s_R[(MA + 2 * k + 1) * 64 + lane];
        s_R[(MA + 2 * k) * 64 + lane]     = fmaf(x0, D2[k].x, U2[k].x);
        s_R[(MA + 2 * k + 1) * 64 + lane] = fmaf(x1, D2[k].y, U2[k].y);
        mv2[MA / 2 + k].x = x0; mv2[MA / 2 + k].y = x1;
      }
    }
    __syncthreads();
  }

  // ---- phase 3: replay chunks 1..7 from boundary states ----
  if (wave > 0) replay(tb);
}

// ---------------- K4: parallel summary GEMM + heads + CORAL over all (b,t) ----------------
__global__ __launch_bounds__(256) void k_head(
    const int* __restrict__ q_data,
    const _Float16* __restrict__ Rd, const _Float16* __restrict__ Wh,
    const float* __restrict__ Sq_tab, const float* __restrict__ aq_tab,
    const float* __restrict__ beta_tab,
    const float* __restrict__ W_theta, const float* __restrict__ b_theta,
    const float* __restrict__ W_disc, const float* __restrict__ b_disc,
    const float* __restrict__ W_c1, const float* __restrict__ b_c1,
    const float* __restrict__ W_c2, const float* __restrict__ b_c2,
    const float* __restrict__ coral_w, const float* __restrict__ coral_b,
    float* __restrict__ out)
{
  const int tid = threadIdx.x;
  const int w = tid >> 6, l = tid & 63;
  const int rowbase = blockIdx.x * 64;           // 64 rows (same b: 64 | 1024)
  const int b = rowbase >> 10;
  const int t0 = rowbase & (SS - 1);

  __shared__ __align__(16) _Float16 s_A[64 * 256];   // 32 KB
  __shared__ __align__(16) _Float16 s_sum[64 * 128]; // 16 KB
  __shared__ int   s_q[64];
  __shared__ float s_aq[64];
  __shared__ float s_be[64][3];

  {
    const uint4* src = (const uint4*)(Rd + (size_t)rowbase * VDIM);
    uint4* dst = (uint4*)s_A;
    for (int i = tid; i < (64 * 256 * 2) / 16; i += 256) dst[i] = src[i];
  }
  if (tid < 64) {
    const int q = q_data[b * SS + t0 + tid];
    s_q[tid] = q;
    s_aq[tid] = aq_tab[q];
    s_be[tid][0] = beta_tab[(size_t)q * 3 + 0];
    s_be[tid][1] = beta_tab[(size_t)q * 3 + 1];
    s_be[tid][2] = beta_tab[(size_t)q * 3 + 2];
  }

  const int fp = l >> 1, g = l & 1;
  const int fbase = (w & 1) * 64;
  const int f0 = fbase + 2 * fp, f1 = f0 + 1;
  U4 wr0[16], wr1[16];
  {
    const uint4* p0 = (const uint4*)(Wh + (size_t)f0 * 256 + g * 128);
    const uint4* p1 = (const uint4*)(Wh + (size_t)f1 * 256 + g * 128);
#pragma unroll
    for (int i = 0; i < 16; ++i) { wr0[i].u = p0[i]; wr1[i].u = p1[i]; }
  }
  __syncthreads();

  for (int rp = 0; rp < 32; ++rp) {
    const int r = 2 * rp + (w >> 1);
    const uint4* a4 = (const uint4*)(s_A + r * 256 + g * 128);
    float a0 = 0.f, a1 = 0.f, c0 = 0.f, c1 = 0.f;
#pragma unroll
    for (int i = 0; i < 16; i += 2) {
      U4 x; x.u = a4[i];
      U4 y; y.u = a4[i + 1];
#pragma unroll
      for (int j = 0; j < 4; ++j) {
        a0 = dot2_(x.h[j], wr0[i].h[j], a0);
        a1 = dot2_(x.h[j], wr1[i].h[j], a1);
        c0 = dot2_(y.h[j], wr0[i + 1].h[j], c0);
        c1 = dot2_(y.h[j], wr1[i + 1].h[j], c1);
      }
    }
    float f0acc = a0 + c0, f1acc = a1 + c1;
    f0acc += __shfl_xor(f0acc, 1);
    f1acc += __shfl_xor(f1acc, 1);
    if (g == 0) {
      const float2 sq = *(const float2*)(Sq_tab + (size_t)s_q[r] * FDIM + f0);
      s_sum[r * 128 + f0] = (_Float16)tanhf(f0acc + sq.x);
      s_sum[r * 128 + f1] = (_Float16)tanhf(f1acc + sq.y);
    }
  }
  __syncthreads();

  const float tw0 = W_theta[l], tw1 = W_theta[64 + l], tb = b_theta[0];
  const float dw0 = W_disc[l], dw1 = W_disc[64 + l], db = b_disc[0];
  float wc1reg[5];
#pragma unroll
  for (int i = 0; i < 5; ++i) wc1reg[i] = W_c1[i * 64 + l];
  const float bc1 = b_c1[l];
  const int jj = l >> 1, hh2 = l & 1;
  float wc2reg[32];
#pragma unroll
  for (int i = 0; i < 32; ++i) wc2reg[i] = W_c2[(hh2 * 32 + i) * 32 + jj];
  const float bc2 = b_c2[jj];
  const float cw = coral_w[jj];
  const float cb0 = coral_b[0], cb1 = coral_b[1], cb2 = coral_b[2];

  float* out_theta = out;
  float* out_beta  = out + (size_t)BB * SS;
  float* out_alpha = out + (size_t)BB * SS * 4;
  float* out_probs = out + (size_t)BB * SS * 5;
  float* out_logit = out + (size_t)BB * SS * 9;

  for (int rr = 0; rr < 16; ++rr) {
    const int r = w * 16 + rr;
    const float su0 = (float)s_sum[r * 128 + l];
    const float su1 = (float)s_sum[r * 128 + 64 + l];
    float at = su0 * tw0 + su1 * tw1;
    float ad = su0 * dw0 + su1 * dw1;
#pragma unroll
    for (int o = 32; o; o >>= 1) { at += __shfl_xor(at, o); ad += __shfl_xor(ad, o); }
    const float theta = (at + tb) * 3.0f;
    const float alpha = softplusf_(ad + s_aq[r] + db);
    const float be0 = s_be[r][0], be1 = s_be[r][1], be2 = s_be[r][2];
    float h1 = bc1;
    h1 = fmaf(theta, wc1reg[0], h1);
    h1 = fmaf(alpha, wc1reg[1], h1);
    h1 = fmaf(be0, wc1reg[2], h1);
    h1 = fmaf(be1, wc1reg[3], h1);
    h1 = fmaf(be2, wc1reg[4], h1);
    h1 = fmaxf(h1, 0.f);
    float hacc = hh2 ? 0.f : bc2;
#pragma unroll
    for (int i = 0; i < 32; ++i)
      hacc = fmaf(__shfl(h1, hh2 * 32 + i), wc2reg[i], hacc);
    hacc += __shfl_xor(hacc, 1);
    const float h2 = fmaxf(hacc, 0.f);
    float p = h2 * cw * 0.5f;
#pragma unroll
    for (int o = 32; o; o >>= 1) p += __shfl_xor(p, o);
    if (l == 0) {
      const float z = p;
      const float l0 = z + cb0, l1 = z + cb1, l2 = z + cb2;
      const float s0 = sigmoidf_(l0), s1 = sigmoidf_(l1), s2 = sigmoidf_(l2);
      const float q0 = s0, q1 = s0 * s1, q2 = s0 * s1 * s2;
      const size_t bt = (size_t)rowbase + r;
      out_theta[bt] = theta;
      out_alpha[bt] = alpha;
      out_beta[bt * 3 + 0] = be0;
      out_beta[bt * 3 + 1] = be1;
      out_beta[bt * 3 + 2] = be2;
      out_logit[bt * 3 + 0] = l0;
      out_logit[bt * 3 + 1] = l1;
      out_logit[bt * 3 + 2] = l2;
      out_probs[bt * 4 + 0] = 1.f - q0;
      out_probs[bt * 4 + 1] = q0 - q1;
      out_probs[bt * 4 + 2] = q1 - q2;
      out_probs[bt * 4 + 3] = q2;
    }
  }
}

extern "C" void kernel_launch(void* const* d_in, const int* in_sizes, int n_in,
                              void* d_out, int out_size, void* d_ws, size_t ws_size,
                              hipStream_t stream) {
  const int*   q_data    = (const int*)d_in[0];
  const int*   r_data    = (const int*)d_in[1];
  const float* q_embed   = (const float*)d_in[2];
  const float* key_mem   = (const float*)d_in[3];
  const float* init_mv   = (const float*)d_in[4];
  const float* W_value   = (const float*)d_in[5];
  const float* b_value   = (const float*)d_in[6];
  const float* W_erase   = (const float*)d_in[7];
  const float* b_erase   = (const float*)d_in[8];
  const float* W_add     = (const float*)d_in[9];
  const float* b_add     = (const float*)d_in[10];
  const float* W_summary = (const float*)d_in[11];
  const float* b_summary = (const float*)d_in[12];
  const float* W_theta   = (const float*)d_in[13];
  const float* b_theta   = (const float*)d_in[14];
  const float* W_beta    = (const float*)d_in[15];
  const float* b_beta    = (const float*)d_in[16];
  const float* W_disc    = (const float*)d_in[17];
  const float* b_disc    = (const float*)d_in[18];
  const float* W_c1      = (const float*)d_in[19];
  const float* b_c1      = (const float*)d_in[20];
  const float* W_c2      = (const float*)d_in[21];
  const float* b_c2      = (const float*)d_in[22];
  const float* coral_w   = (const float*)d_in[23];
  const float* coral_b   = (const float*)d_in[24];

  float* ws = (float*)d_ws;
  size_t off = 0;
  float2* EA      = (float2*)(ws + off); off += (size_t)RROWS * VDIM * 2;
  float* w_tab    = ws + off; off += (size_t)QD * MM;
  float* Sq_tab   = ws + off; off += (size_t)QD * FDIM;
  float* aq_tab   = ws + off; off += 5120;
  float* beta_tab = ws + off; off += 15104;
  _Float16* Wh = (_Float16*)(ws + off); off += (VDIM * FDIM) / 2;
  _Float16* Rd = (_Float16*)(ws + off);

  k_prep<<<dim3(128), dim3(256), 0, stream>>>(W_summary, Wh);

  k_ea<<<dim3((RROWS + 31) / 32), dim3(256), 0, stream>>>(
      W_value, b_value, W_erase, b_erase, W_add, b_add, EA);

  k_q<<<dim3(QD), dim3(256), 0, stream>>>(
      q_embed, key_mem, W_summary, b_summary, W_disc, W_beta, b_beta,
      w_tab, Sq_tab, aq_tab, beta_tab);

  k_rec6<<<dim3(BB * 4), dim3(512), 0, stream>>>(
      q_data, r_data, init_mv, EA, w_tab, Rd);

  k_head<<<dim3((BB * SS) / 64), dim3(256), 0, stream>>>(
      q_data, Rd, Wh, Sq_tab, aq_tab, beta_tab,
      W_theta, b_theta, W_disc, b_disc,
      W_c1, b_c1, W_c2, b_c2, coral_w, coral_b, (float*)d_out);
}